// Round 5
// baseline (718.231 us; speedup 1.0000x reference)
//
#include <hip/hip_runtime.h>
#include <hip/hip_bf16.h>

typedef __bf16 bf16;
typedef __attribute__((ext_vector_type(4))) __bf16 bf16x4;
typedef __attribute__((ext_vector_type(8))) __bf16 bf16x8;
typedef __attribute__((ext_vector_type(4))) float f32x4;

__device__ inline void gload_lds16(const bf16* g, bf16* l) {
    __builtin_amdgcn_global_load_lds(
        (const __attribute__((address_space(1))) void*)g,
        (__attribute__((address_space(3))) void*)l, 16, 0, 0);
}

// ---------------------------------------------------------------- fused conversions
struct CvtArgs {
    const float* src[6];
    bf16* dst[6];
    long n4[6];
    float scale[6];
};
__global__ void cvt_all(CvtArgs a) {
    int j = blockIdx.y;
    const float* __restrict__ src = a.src[j];
    bf16* __restrict__ dst = a.dst[j];
    long n4 = a.n4[j];
    float sc = a.scale[j];
    long i = (long)blockIdx.x * blockDim.x + threadIdx.x;
    long stride = (long)gridDim.x * blockDim.x;
    for (; i < n4; i += stride) {
        float4 v = ((const float4*)src)[i];
        bf16x4 o = { (bf16)(v.x * sc), (bf16)(v.y * sc), (bf16)(v.z * sc), (bf16)(v.w * sc) };
        ((bf16x4*)dst)[i] = o;
    }
}

// ---------------------------------------------------------------- embedding
__global__ void embed_kernel(const int* __restrict__ x, const float* __restrict__ we,
                             const float* __restrict__ pe, float* __restrict__ emb_f,
                             bf16* __restrict__ emb_b) {
    int row = blockIdx.x;            // 0..8191  (b*2048 + s)
    int c   = threadIdx.x;           // 0..127
    int tok = x[row];
    int s   = row & 2047;
    float4 w = ((const float4*)we)[(long)tok * 128 + c];
    float4 p = ((const float4*)pe)[(long)s * 128 + c];
    float4 e = { w.x + p.x, w.y + p.y, w.z + p.z, w.w + p.w };
    ((float4*)emb_f)[(long)row * 128 + c] = e;
    bf16x4 eb = { (bf16)e.x, (bf16)e.y, (bf16)e.z, (bf16)e.w };
    ((bf16x4*)emb_b)[(long)row * 128 + c] = eb;
}

// ---------------------------------------------------------------- layernorm
template<bool WF32>
__global__ void ln_kernel(const float* __restrict__ a, const float* __restrict__ bres,
                          const float* __restrict__ g, const float* __restrict__ bb,
                          float* __restrict__ of, bf16* __restrict__ ob) {
    int row = blockIdx.x;            // 8192
    int t   = threadIdx.x;           // 128
    float4 xa = ((const float4*)a)[(long)row * 128 + t];
    float4 xb = ((const float4*)bres)[(long)row * 128 + t];
    float4 xv = { xa.x + xb.x, xa.y + xb.y, xa.z + xb.z, xa.w + xb.w };
    float s  = xv.x + xv.y + xv.z + xv.w;
    float sq = xv.x * xv.x + xv.y * xv.y + xv.z * xv.z + xv.w * xv.w;
    #pragma unroll
    for (int o = 32; o > 0; o >>= 1) {
        s  += __shfl_xor(s, o);
        sq += __shfl_xor(sq, o);
    }
    __shared__ float rs[2], rq[2];
    int wid = t >> 6;
    if ((t & 63) == 0) { rs[wid] = s; rq[wid] = sq; }
    __syncthreads();
    s = rs[0] + rs[1]; sq = rq[0] + rq[1];
    float mu   = s * (1.0f / 512.0f);
    float var  = sq * (1.0f / 512.0f) - mu * mu;
    float rstd = rsqrtf(var + 1e-5f);
    float4 gv = ((const float4*)g)[t];
    float4 bv = ((const float4*)bb)[t];
    float4 y = { (xv.x - mu) * rstd * gv.x + bv.x,
                 (xv.y - mu) * rstd * gv.y + bv.y,
                 (xv.z - mu) * rstd * gv.z + bv.z,
                 (xv.w - mu) * rstd * gv.w + bv.w };
    if (WF32) ((float4*)of)[(long)row * 128 + t] = y;
    bf16x4 yb = { (bf16)y.x, (bf16)y.y, (bf16)y.z, (bf16)y.w };
    ((bf16x4*)ob)[(long)row * 128 + t] = yb;
}

// ---------------------------------------------------------------- causal softmax
__global__ void softmax_causal(const float* __restrict__ sc, bf16* __restrict__ pr) {
    int row = blockIdx.x;            // 8192
    int z = row >> 11, q = row & 2047;
    const float* srow = sc + ((long)z * 2048 + q) * 2048;
    bf16*        prow = pr + ((long)z * 2048 + q) * 2048;
    int t = threadIdx.x;             // 256, each handles 8 cols
    float v[8];
    int c0 = t * 8;
    if (t <= (q >> 3)) {
        float4 v0 = ((const float4*)srow)[t * 2];
        float4 v1 = ((const float4*)srow)[t * 2 + 1];
        v[0] = v0.x; v[1] = v0.y; v[2] = v0.z; v[3] = v0.w;
        v[4] = v1.x; v[5] = v1.y; v[6] = v1.z; v[7] = v1.w;
    } else {
        #pragma unroll
        for (int j = 0; j < 8; j++) v[j] = -1e30f;
    }
    float mx = -1e30f;
    #pragma unroll
    for (int j = 0; j < 8; j++) {
        if (c0 + j > q) v[j] = -1e30f;
        mx = fmaxf(mx, v[j]);
    }
    int lane = t & 63, wid = t >> 6;
    #pragma unroll
    for (int o = 32; o > 0; o >>= 1) mx = fmaxf(mx, __shfl_xor(mx, o));
    __shared__ float redm[4], reds[4];
    if (lane == 0) redm[wid] = mx;
    __syncthreads();
    mx = fmaxf(fmaxf(redm[0], redm[1]), fmaxf(redm[2], redm[3]));
    float p[8]; float sum = 0.f;
    #pragma unroll
    for (int j = 0; j < 8; j++) {
        p[j] = (c0 + j <= q) ? __expf(v[j] - mx) : 0.f;
        sum += p[j];
    }
    #pragma unroll
    for (int o = 32; o > 0; o >>= 1) sum += __shfl_xor(sum, o);
    if (lane == 0) reds[wid] = sum;
    __syncthreads();
    sum = reds[0] + reds[1] + reds[2] + reds[3];
    float inv = 1.0f / sum;
    int wlim = ((q >> 7) + 1) * 128;             // causal 128-block boundary
    if (c0 < wlim) {
        bf16x8 o;
        #pragma unroll
        for (int j = 0; j < 8; j++) o[j] = (bf16)(p[j] * inv);
        *(bf16x8*)&prow[c0] = o;
    }
}

// ---------------------------------------------------------------- epilogue tags
enum { EPI_F32 = 0, EPI_BF16 = 1, EPI_VT = 2, EPI_BIAS_RELU_BF16 = 3, EPI_BIAS_F32 = 4,
       EPI_QKV = 5 };
enum { ZB_BATCH = 0 };

// ---------------------------------------------------------------- 128^2 GEMM (proven)
template<int EPI, bool CAUSAL_SKIP, bool CAUSAL_K, bool XCD, int ZMODE>
__global__ __launch_bounds__(256)
void gemm_bt(const bf16* __restrict__ A, const bf16* __restrict__ B,
             float* __restrict__ Cf, bf16* __restrict__ Cb,
             const float* __restrict__ bias, float scale,
             int M, int N, int K, int Krow, long sA, long sB, long sC) {
    int br, bc;
    if (XCD) {
        int nwg = gridDim.x * gridDim.y;         // caller ensures %8==0
        int lin = blockIdx.y * gridDim.x + blockIdx.x;
        lin = (lin & 7) * (nwg >> 3) + (lin >> 3);
        br = lin / gridDim.x; bc = lin - br * gridDim.x;
    } else { br = blockIdx.y; bc = blockIdx.x; }
    int z = blockIdx.z;
    A += (long)z * sA; B += (long)z * sB; Cf += (long)z * sC;
    if (CAUSAL_SKIP && bc > br) return;
    int Kext = CAUSAL_K ? min(K, (br + 1) * 128) : K;
    __shared__ bf16 As[128 * 64];
    __shared__ bf16 Bs[128 * 64];
    int tid = threadIdx.x;
    int lane = tid & 63, wid = tid >> 6;
    int wm = (wid >> 1) * 64, wn = (wid & 1) * 64;
    f32x4 acc[4][4] = {};
    int rowA0 = br * 128, colB0 = bc * 128;
    int rsub = lane >> 3;
    int csub = ((lane & 7) ^ rsub) * 8;            // pre-swizzled source col
    int rdsw = (lane & 7) * 8;                     // read-side XOR
    for (int kt = 0; kt < Kext; kt += 64) {
        const bf16* Ag = A + (long)rowA0 * Krow + kt;
        const bf16* Bg = B + (long)colB0 * Krow + kt;
        #pragma unroll
        for (int i = 0; i < 4; i++) {
            int seg = wid * 4 + i;
            int r = seg * 8 + rsub;
            gload_lds16(&Ag[(long)r * Krow + csub], &As[seg * 512]);
            gload_lds16(&Bg[(long)r * Krow + csub], &Bs[seg * 512]);
        }
        __syncthreads();
        #pragma unroll
        for (int kk = 0; kk < 2; kk++) {
            bf16x8 af[4], bfr[4];
            int ko = (kk * 32 + (lane >> 4) * 8) ^ rdsw;
            #pragma unroll
            for (int m = 0; m < 4; m++) af[m]  = *(const bf16x8*)&As[(wm + m * 16 + (lane & 15)) * 64 + ko];
            #pragma unroll
            for (int n = 0; n < 4; n++) bfr[n] = *(const bf16x8*)&Bs[(wn + n * 16 + (lane & 15)) * 64 + ko];
            #pragma unroll
            for (int m = 0; m < 4; m++)
                #pragma unroll
                for (int n = 0; n < 4; n++)
                    acc[m][n] = __builtin_amdgcn_mfma_f32_16x16x32_bf16(af[m], bfr[n], acc[m][n], 0, 0, 0);
        }
        __syncthreads();
    }
    #pragma unroll
    for (int m = 0; m < 4; m++) {
        #pragma unroll
        for (int n = 0; n < 4; n++) {
            #pragma unroll
            for (int j = 0; j < 4; j++) {
                int row = rowA0 + wm + m * 16 + (lane >> 4) * 4 + j;
                int col = colB0 + wn + n * 16 + (lane & 15);
                float v = acc[m][n][j];
                if (EPI == EPI_F32) {
                    Cf[(long)row * N + col] = v;        // z-offset already applied
                } else if (EPI == EPI_BF16) {
                    Cb[(long)row * N + col] = (bf16)(v * scale);
                } else if (EPI == EPI_VT) {
                    int b = row >> 11, k = row & 2047;
                    Cb[((long)b * 512 + col) * 2048 + k] = (bf16)v;
                } else if (EPI == EPI_BIAS_RELU_BF16) {
                    float y = fmaxf(v + bias[col], 0.0f);
                    Cb[(long)row * N + col] = (bf16)y;
                } else if (EPI == EPI_BIAS_F32) {
                    Cf[(long)row * N + col] = v + bias[col];
                }
            }
        }
    }
}

// ---------------------------------------------------------------- 256^2 deep-pipeline GEMM (BK=64)
template<int EPI, bool XCD, bool CSKIP, int NT>
__global__ __launch_bounds__(512)
void gemm256(const bf16* __restrict__ A, const bf16* __restrict__ B,
             float* __restrict__ Cf, bf16* __restrict__ Cb,
             const float* __restrict__ bias, int N, int K,
             long sA, long sB, long sC) {
    int br, bc;
    if (XCD) {
        int nwg = gridDim.x * gridDim.y;          // caller ensures %8==0
        int lin = blockIdx.y * gridDim.x + blockIdx.x;
        lin = (lin & 7) * (nwg >> 3) + (lin >> 3);
        br = lin / gridDim.x; bc = lin - br * gridDim.x;
    } else { br = blockIdx.y; bc = blockIdx.x; }
    if (CSKIP && bc > br) return;                 // causal skip at 256-tile granularity
    int z = blockIdx.z;
    A  += (long)z * sA;
    B  += (long)z * sB;
    Cf += (long)z * sC;
    __shared__ bf16 lds[2][2][256 * 64];          // [buf][A/B] = 128 KiB
    int tid = threadIdx.x;
    int lane = tid & 63, wid = tid >> 6;
    int wm2 = wid >> 2, wn4 = wid & 3;
    long rowA0 = (long)br * 256, colB0 = (long)bc * 256;
    int rsub = lane >> 3;
    int csw  = ((lane & 7) ^ rsub) * 8;           // pre-swizzled source col
    int l15 = lane & 15;
    int rdxor = (lane & 7) << 3;
    int kbase = (lane >> 4) * 8;
    const bf16* Abase = A + rowA0 * K;
    const bf16* Bbase = B + colB0 * K;
    f32x4 acc[8][4] = {};

    auto stage = [&](int t) {
        int buf = t & 1;
        const bf16* Ag = Abase + t * 64;
        const bf16* Bg = Bbase + t * 64;
        #pragma unroll
        for (int i = 0; i < 4; i++) {
            int seg = wid * 4 + i;                // 0..31
            long r = seg * 8 + rsub;
            gload_lds16(&Ag[r * K + csw], &lds[buf][0][seg * 512]);
        }
        #pragma unroll
        for (int i = 0; i < 4; i++) {
            int seg = wid * 4 + i;
            long r = seg * 8 + rsub;
            gload_lds16(&Bg[r * K + csw], &lds[buf][1][seg * 512]);
        }
    };

    stage(0);
    stage(1);

    for (int t = 0; t < NT; t++) {
        int buf = t & 1;
        if (t == NT - 1) asm volatile("s_waitcnt vmcnt(0)" ::: "memory");
        else             asm volatile("s_waitcnt vmcnt(8)" ::: "memory");
        __builtin_amdgcn_s_barrier();             // everyone's tile-t data visible
        const bf16* As = lds[buf][0];
        const bf16* Bs = lds[buf][1];
        bf16x8 bfr[2][4], af[2][4];
        #pragma unroll
        for (int kk = 0; kk < 2; kk++)
            #pragma unroll
            for (int n = 0; n < 4; n++) {
                int r = wn4 * 64 + n * 16 + l15;
                bfr[kk][n] = *(const bf16x8*)&Bs[r * 64 + ((kk * 32 + kbase) ^ rdxor)];
            }
        #pragma unroll
        for (int kk = 0; kk < 2; kk++)
            #pragma unroll
            for (int m = 0; m < 4; m++) {
                int r = wm2 * 128 + m * 16 + l15;
                af[kk][m] = *(const bf16x8*)&As[r * 64 + ((kk * 32 + kbase) ^ rdxor)];
            }
        __builtin_amdgcn_s_setprio(1);
        #pragma unroll
        for (int kk = 0; kk < 2; kk++)
            #pragma unroll
            for (int m = 0; m < 4; m++)
                #pragma unroll
                for (int n = 0; n < 4; n++)
                    acc[m][n] = __builtin_amdgcn_mfma_f32_16x16x32_bf16(af[kk][m], bfr[kk][n], acc[m][n], 0, 0, 0);
        __builtin_amdgcn_s_setprio(0);
        // second half of A rows
        #pragma unroll
        for (int kk = 0; kk < 2; kk++)
            #pragma unroll
            for (int m = 0; m < 4; m++) {
                int r = wm2 * 128 + 64 + m * 16 + l15;
                af[kk][m] = *(const bf16x8*)&As[r * 64 + ((kk * 32 + kbase) ^ rdxor)];
            }
        asm volatile("s_waitcnt lgkmcnt(0)" ::: "memory"); // all my buf reads done
        __builtin_amdgcn_sched_barrier(0);
        __builtin_amdgcn_s_barrier();             // ALL waves done reading buf
        if (t + 2 < NT) stage(t + 2);             // overwrite buf; flies across iters
        __builtin_amdgcn_s_setprio(1);
        #pragma unroll
        for (int kk = 0; kk < 2; kk++)
            #pragma unroll
            for (int m = 0; m < 4; m++)
                #pragma unroll
                for (int n = 0; n < 4; n++)
                    acc[4 + m][n] = __builtin_amdgcn_mfma_f32_16x16x32_bf16(af[kk][m], bfr[kk][n], acc[4 + m][n], 0, 0, 0);
        __builtin_amdgcn_s_setprio(0);
    }

    if constexpr (EPI == EPI_QKV) {
        // N=1536; 256-col panels are block-uniform: 0-1=Q, 2-3=K, 4-5=V.
        int region = (int)(colB0 >> 9);           // 0=Q, 1=K, 2=V
        if (region < 2) {
            bf16* dst = Cb + (long)region * (8192L * 512);
            int cb = ((int)colB0 & 511) + wn4 * 64;
            #pragma unroll
            for (int m = 0; m < 8; m++)
                #pragma unroll
                for (int n = 0; n < 4; n++)
                    #pragma unroll
                    for (int j = 0; j < 4; j++) {
                        long row = rowA0 + wm2 * 128 + m * 16 + (lane >> 4) * 4 + j;
                        int c = cb + n * 16 + l15;
                        dst[row * 512 + c] = (bf16)acc[m][n][j];
                    }
        } else {
            bf16* vtb = Cb + 2L * 8192 * 512;
            int cb = ((int)colB0 - 1024) + wn4 * 64;
            #pragma unroll
            for (int m = 0; m < 8; m++)
                #pragma unroll
                for (int n = 0; n < 4; n++) {
                    long k0 = rowA0 + wm2 * 128 + m * 16 + (lane >> 4) * 4;
                    long b = k0 >> 11, k = k0 & 2047;
                    int c = cb + n * 16 + l15;
                    bf16x4 pk = { (bf16)acc[m][n][0], (bf16)acc[m][n][1],
                                  (bf16)acc[m][n][2], (bf16)acc[m][n][3] };
                    *(bf16x4*)&vtb[(b * 512 + c) * 2048 + k] = pk;
                }
        }
    } else {
        #pragma unroll
        for (int m = 0; m < 8; m++) {
            #pragma unroll
            for (int n = 0; n < 4; n++) {
                #pragma unroll
                for (int j = 0; j < 4; j++) {
                    long row = rowA0 + wm2 * 128 + m * 16 + (lane >> 4) * 4 + j;
                    long col = colB0 + wn4 * 64 + n * 16 + l15;
                    float v = acc[m][n][j];
                    if (EPI == EPI_BIAS_F32) {
                        Cf[row * N + col] = v + bias[col];
                    } else if (EPI == EPI_BIAS_RELU_BF16) {
                        Cb[row * N + col] = (bf16)fmaxf(v + bias[col], 0.0f);
                    } else if (EPI == EPI_F32) {
                        Cf[row * N + col] = v;
                    }
                }
            }
        }
    }
}

// ---------------------------------------------------------------- persistent vocab GEMM
// 256 blocks (1/CU), each processes ~15-16 output tiles (256x256) with the
// proven 8-phase pipeline FLATTENED across tile boundaries: next tile's loads
// are in flight before this tile's epilogue stores, so store drain overlaps
// compute. vmcnt discipline: issue order per iter = [stage(T+2) 8 loads]
// [boundary: 32 stores]; in-order counter retirement => grace window: the two
// iterations after a boundary wait vmcnt(40)=8 loads+32 stores; vmcnt(8)
// after that. Bias served from LDS (lgkmcnt path; keeps vmcnt clean).
// Unit map: XCD x owns units u'=0..499 (br=4x+u'/125, bc=u'%125); its 32
// blocks take u' = k+32j => concurrent blocks share one A tile (L2) and
// write 32 adjacent 1KB column stripes of the same rows (DRAM locality).
__global__ __launch_bounds__(512)
void gemm256pv(const bf16* __restrict__ A, const bf16* __restrict__ B,
               float* __restrict__ C, const float* __restrict__ bias) {
    const int K = 512, N = 32000, NT = 8;
    int xcd = blockIdx.x & 7, kk0 = blockIdx.x >> 3;  // kk0 in 0..31
    int nj = ((499 - kk0) >> 5) + 1;                  // 15 or 16 units
    int TT = nj * NT;
    __shared__ bf16 lds[2][2][256 * 64];              // 128 KiB
    __shared__ float bias_lds[16 * 256];              // 16 KiB
    int tid = threadIdx.x;
    int lane = tid & 63, wid = tid >> 6;
    int wm2 = wid >> 2, wn4 = wid & 3;
    int rsub = lane >> 3;
    int csw  = ((lane & 7) ^ rsub) * 8;
    int l15 = lane & 15;
    int rdxor = (lane & 7) << 3;
    int kbase = (lane >> 4) * 8;

    // stage all my units' bias rows into LDS (vmcnt drained before pipeline)
    for (int j = 0; j < nj; j++) {
        int u = kk0 + 32 * j;
        if (tid < 256) bias_lds[j * 256 + tid] = bias[(u % 125) * 256 + tid];
    }
    asm volatile("s_waitcnt vmcnt(0) lgkmcnt(0)" ::: "memory");

    auto stage = [&](int T) {
        int buf = T & 1;
        int t = T & 7, j = T >> 3;
        int u = kk0 + 32 * j;
        long br = 4 * xcd + u / 125;
        long bc = u % 125;
        const bf16* Ag = A + (br * 256) * (long)K + t * 64;
        const bf16* Bg = B + (bc * 256) * (long)K + t * 64;
        #pragma unroll
        for (int i = 0; i < 4; i++) {
            int seg = wid * 4 + i;
            long r = seg * 8 + rsub;
            gload_lds16(&Ag[r * K + csw], &lds[buf][0][seg * 512]);
        }
        #pragma unroll
        for (int i = 0; i < 4; i++) {
            int seg = wid * 4 + i;
            long r = seg * 8 + rsub;
            gload_lds16(&Bg[r * K + csw], &lds[buf][1][seg * 512]);
        }
    };

    stage(0);
    stage(1);
    f32x4 acc[8][4] = {};

    for (int T = 0; T < TT; T++) {
        int buf = T & 1, tmod = T & 7;
        if (T == TT - 1)              asm volatile("s_waitcnt vmcnt(0)" ::: "memory");
        else if (T >= 2 && tmod <= 1) asm volatile("s_waitcnt vmcnt(40)" ::: "memory");
        else                          asm volatile("s_waitcnt vmcnt(8)" ::: "memory");
        __builtin_amdgcn_s_barrier();             // tile-T data visible
        const bf16* As = lds[buf][0];
        const bf16* Bs = lds[buf][1];
        bf16x8 bfr[2][4], af[2][4];
        #pragma unroll
        for (int kk = 0; kk < 2; kk++)
            #pragma unroll
            for (int n = 0; n < 4; n++) {
                int r = wn4 * 64 + n * 16 + l15;
                bfr[kk][n] = *(const bf16x8*)&Bs[r * 64 + ((kk * 32 + kbase) ^ rdxor)];
            }
        #pragma unroll
        for (int kk = 0; kk < 2; kk++)
            #pragma unroll
            for (int m = 0; m < 4; m++) {
                int r = wm2 * 128 + m * 16 + l15;
                af[kk][m] = *(const bf16x8*)&As[r * 64 + ((kk * 32 + kbase) ^ rdxor)];
            }
        __builtin_amdgcn_s_setprio(1);
        #pragma unroll
        for (int kk = 0; kk < 2; kk++)
            #pragma unroll
            for (int m = 0; m < 4; m++)
                #pragma unroll
                for (int n = 0; n < 4; n++)
                    acc[m][n] = __builtin_amdgcn_mfma_f32_16x16x32_bf16(af[kk][m], bfr[kk][n], acc[m][n], 0, 0, 0);
        __builtin_amdgcn_s_setprio(0);
        // second half of A rows
        #pragma unroll
        for (int kk = 0; kk < 2; kk++)
            #pragma unroll
            for (int m = 0; m < 4; m++) {
                int r = wm2 * 128 + 64 + m * 16 + l15;
                af[kk][m] = *(const bf16x8*)&As[r * 64 + ((kk * 32 + kbase) ^ rdxor)];
            }
        asm volatile("s_waitcnt lgkmcnt(0)" ::: "memory"); // my buf reads done
        __builtin_amdgcn_sched_barrier(0);
        __builtin_amdgcn_s_barrier();             // ALL waves done reading buf
        if (T + 2 < TT) stage(T + 2);             // next tiles fly across boundary
        __builtin_amdgcn_s_setprio(1);
        #pragma unroll
        for (int kk = 0; kk < 2; kk++)
            #pragma unroll
            for (int m = 0; m < 4; m++)
                #pragma unroll
                for (int n = 0; n < 4; n++)
                    acc[4 + m][n] = __builtin_amdgcn_mfma_f32_16x16x32_bf16(af[kk][m], bfr[kk][n], acc[4 + m][n], 0, 0, 0);
        __builtin_amdgcn_s_setprio(0);
        if (tmod == NT - 1) {                     // unit complete: epilogue
            int j = T >> 3;
            int u = kk0 + 32 * j;
            long row0 = (long)(4 * xcd + u / 125) * 256 + wm2 * 128;
            long col0 = (long)(u % 125) * 256 + wn4 * 64;
            float brow[4];
            #pragma unroll
            for (int n = 0; n < 4; n++)
                brow[n] = bias_lds[j * 256 + wn4 * 64 + n * 16 + l15];
            #pragma unroll
            for (int m = 0; m < 8; m++)
                #pragma unroll
                for (int n = 0; n < 4; n++)
                    #pragma unroll
                    for (int jj = 0; jj < 4; jj++) {
                        long row = row0 + m * 16 + (lane >> 4) * 4 + jj;
                        C[row * N + col0 + n * 16 + l15] = acc[m][n][jj] + brow[n];
                    }
            #pragma unroll
            for (int m = 0; m < 8; m++)
                #pragma unroll
                for (int n = 0; n < 4; n++)
                    acc[m][n] = f32x4{ 0.f, 0.f, 0.f, 0.f };
        }
    }
}

// ---------------------------------------------------------------- launch
extern "C" void kernel_launch(void* const* d_in, const int* in_sizes, int n_in,
                              void* d_out, int out_size, void* d_ws, size_t ws_size,
                              hipStream_t stream) {
    const int*   x       = (const int*)d_in[0];
    const float* word_emb = (const float*)d_in[1];
    const float* pos_emb  = (const float*)d_in[2];
    const float* Wq = (const float*)d_in[3];
    const float* Wk = (const float*)d_in[4];
    const float* Wv = (const float*)d_in[5];
    const float* g1 = (const float*)d_in[6];
    const float* b1 = (const float*)d_in[7];
    const float* w_ffn1 = (const float*)d_in[8];
    const float* b_ffn1 = (const float*)d_in[9];
    const float* w_ffn2 = (const float*)d_in[10];
    const float* b_ffn2 = (const float*)d_in[11];
    const float* g2 = (const float*)d_in[12];
    const float* b2 = (const float*)d_in[13];
    const float* w_vocab = (const float*)d_in[14];
    const float* b_vocab = (const float*)d_in[15];
    float* out = (float*)d_out;

    char* w = (char*)d_ws;
    auto alloc = [&](size_t bytes) { char* p = w; w += (bytes + 255) & ~255ULL; return p; };
    // NOTE: wqb/wkb/wvb must stay contiguous ([1536 x 512] fused weight);
    //       qb/kb/vt must stay contiguous (EPI_QKV writes all three off qb).
    bf16* wqb   = (bf16*)alloc(512 * 512 * 2);
    bf16* wkb   = (bf16*)alloc(512 * 512 * 2);
    bf16* wvb   = (bf16*)alloc(512 * 512 * 2);
    bf16* w1b   = (bf16*)alloc(2048 * 512 * 2);
    bf16* w2b   = (bf16*)alloc(512 * 2048 * 2);
    bf16* wvocb = (bf16*)alloc((size_t)32000 * 512 * 2);
    float* embf = (float*)alloc((size_t)8192 * 512 * 4);
    bf16* embb  = (bf16*)alloc((size_t)8192 * 512 * 2);   // also final_b (aliased)
    bf16* qb    = (bf16*)alloc((size_t)8192 * 512 * 2);
    bf16* kb    = (bf16*)alloc((size_t)8192 * 512 * 2);   // also out1_b (aliased)
    bf16* vt    = (bf16*)alloc((size_t)8192 * 512 * 2);
    float* scores = (float*)alloc((size_t)4 * 2048 * 2048 * 4); // also ffn1_b (aliased)
    bf16* probs = (bf16*)alloc((size_t)4 * 2048 * 2048 * 2);
    float* ctx  = (float*)alloc((size_t)8192 * 512 * 4);
    float* out1f = (float*)alloc((size_t)8192 * 512 * 4);
    float* ffn2f = (float*)alloc((size_t)8192 * 512 * 4);
    bf16* ffn1b = (bf16*)scores;   // alias: scores dead after softmax
    bf16* out1b = kb;              // alias: kb dead after scores GEMM
    bf16* finalb = embb;           // alias: embb dead after QKV GEMM

    const float qscale = 0.044194173824159216f; // 1/sqrt(512)

    // one launch converts all six weight tensors (Wq pre-scaled by 1/sqrt(d_k))
    CvtArgs ca;
    ca.src[0] = Wq;      ca.dst[0] = wqb;   ca.n4[0] = 512 * 512 / 4;          ca.scale[0] = qscale;
    ca.src[1] = Wk;      ca.dst[1] = wkb;   ca.n4[1] = 512 * 512 / 4;          ca.scale[1] = 1.0f;
    ca.src[2] = Wv;      ca.dst[2] = wvb;   ca.n4[2] = 512 * 512 / 4;          ca.scale[2] = 1.0f;
    ca.src[3] = w_ffn1;  ca.dst[3] = w1b;   ca.n4[3] = 2048 * 512 / 4;         ca.scale[3] = 1.0f;
    ca.src[4] = w_ffn2;  ca.dst[4] = w2b;   ca.n4[4] = 512 * 2048 / 4;         ca.scale[4] = 1.0f;
    ca.src[5] = w_vocab; ca.dst[5] = wvocb; ca.n4[5] = (long)32000 * 512 / 4;  ca.scale[5] = 1.0f;
    cvt_all<<<dim3(256, 6), 256, 0, stream>>>(ca);

    embed_kernel<<<8192, 128, 0, stream>>>(x, word_emb, pos_emb, embf, embb);

    // fused Q|K|V projection: emb[8192x512] @ Wqkv^T[1536x512] -> qb,kb,vt
    gemm256<EPI_QKV, true, false, 8><<<dim3(6, 32, 1), 512, 0, stream>>>(
        embb, wqb, nullptr, qb, nullptr, 1536, 512, 0, 0, 0);

    // scores = Q @ K^T (batched 256^2 deep pipeline, causal block skip)
    gemm256<EPI_F32, true, true, 8><<<dim3(8, 8, 4), 512, 0, stream>>>(
        qb, kb, scores, nullptr, nullptr, 2048, 512,
        (long)2048 * 512, (long)2048 * 512, (long)2048 * 2048);

    softmax_causal<<<8192, 256, 0, stream>>>(scores, probs);

    // context = P @ V (B operand = V^T, batched, causal K-limit)
    gemm_bt<EPI_F32, false, true, false, ZB_BATCH><<<dim3(4, 16, 4), 256, 0, stream>>>(
        probs, vt, ctx, nullptr, nullptr, 1.0f, 2048, 512, 2048, 2048,
        (long)2048 * 2048, (long)512 * 2048, (long)2048 * 512);

    ln_kernel<true><<<8192, 128, 0, stream>>>(embf, ctx, g1, b1, out1f, out1b);

    // ffn1 = relu(out1 @ W1^T + b1)  -- 256^2 deep pipeline
    gemm256<EPI_BIAS_RELU_BF16, true, false, 8><<<dim3(8, 32, 1), 512, 0, stream>>>(
        out1b, w1b, nullptr, ffn1b, b_ffn1, 2048, 512, 0, 0, 0);

    // ffn2 = ffn1 @ W2^T + b2  (N=512 -> keep 128^2)
    gemm_bt<EPI_BIAS_F32, false, false, false, ZB_BATCH><<<dim3(4, 64, 1), 256, 0, stream>>>(
        ffn1b, w2b, ffn2f, nullptr, b_ffn2, 1.0f, 8192, 512, 2048, 2048, 0, 0, 0);

    ln_kernel<false><<<8192, 128, 0, stream>>>(out1f, ffn2f, g2, b2, nullptr, finalb);

    // logits = final @ w_vocab^T + b_vocab  -- persistent flattened pipeline,
    // 1 block/CU, store drain overlapped with next tile's compute.
    gemm256pv<<<256, 512, 0, stream>>>(finalb, wvocb, out, b_vocab);
}

// Round 6
// 629.621 us; speedup vs baseline: 1.1407x; 1.1407x over previous
//
#include <hip/hip_runtime.h>
#include <hip/hip_bf16.h>

typedef __bf16 bf16;
typedef __attribute__((ext_vector_type(4))) __bf16 bf16x4;
typedef __attribute__((ext_vector_type(8))) __bf16 bf16x8;
typedef __attribute__((ext_vector_type(4))) float f32x4;

__device__ inline void gload_lds16(const bf16* g, bf16* l) {
    __builtin_amdgcn_global_load_lds(
        (const __attribute__((address_space(1))) void*)g,
        (__attribute__((address_space(3))) void*)l, 16, 0, 0);
}

// ---------------------------------------------------------------- fused conversions
struct CvtArgs {
    const float* src[6];
    bf16* dst[6];
    long n4[6];
    float scale[6];
};
__global__ void cvt_all(CvtArgs a) {
    int j = blockIdx.y;
    const float* __restrict__ src = a.src[j];
    bf16* __restrict__ dst = a.dst[j];
    long n4 = a.n4[j];
    float sc = a.scale[j];
    long i = (long)blockIdx.x * blockDim.x + threadIdx.x;
    long stride = (long)gridDim.x * blockDim.x;
    for (; i < n4; i += stride) {
        float4 v = ((const float4*)src)[i];
        bf16x4 o = { (bf16)(v.x * sc), (bf16)(v.y * sc), (bf16)(v.z * sc), (bf16)(v.w * sc) };
        ((bf16x4*)dst)[i] = o;
    }
}

// ---------------------------------------------------------------- embedding
__global__ void embed_kernel(const int* __restrict__ x, const float* __restrict__ we,
                             const float* __restrict__ pe, float* __restrict__ emb_f,
                             bf16* __restrict__ emb_b) {
    int row = blockIdx.x;            // 0..8191  (b*2048 + s)
    int c   = threadIdx.x;           // 0..127
    int tok = x[row];
    int s   = row & 2047;
    float4 w = ((const float4*)we)[(long)tok * 128 + c];
    float4 p = ((const float4*)pe)[(long)s * 128 + c];
    float4 e = { w.x + p.x, w.y + p.y, w.z + p.z, w.w + p.w };
    ((float4*)emb_f)[(long)row * 128 + c] = e;
    bf16x4 eb = { (bf16)e.x, (bf16)e.y, (bf16)e.z, (bf16)e.w };
    ((bf16x4*)emb_b)[(long)row * 128 + c] = eb;
}

// ---------------------------------------------------------------- layernorm
template<bool WF32>
__global__ void ln_kernel(const float* __restrict__ a, const float* __restrict__ bres,
                          const float* __restrict__ g, const float* __restrict__ bb,
                          float* __restrict__ of, bf16* __restrict__ ob) {
    int row = blockIdx.x;            // 8192
    int t   = threadIdx.x;           // 128
    float4 xa = ((const float4*)a)[(long)row * 128 + t];
    float4 xb = ((const float4*)bres)[(long)row * 128 + t];
    float4 xv = { xa.x + xb.x, xa.y + xb.y, xa.z + xb.z, xa.w + xb.w };
    float s  = xv.x + xv.y + xv.z + xv.w;
    float sq = xv.x * xv.x + xv.y * xv.y + xv.z * xv.z + xv.w * xv.w;
    #pragma unroll
    for (int o = 32; o > 0; o >>= 1) {
        s  += __shfl_xor(s, o);
        sq += __shfl_xor(sq, o);
    }
    __shared__ float rs[2], rq[2];
    int wid = t >> 6;
    if ((t & 63) == 0) { rs[wid] = s; rq[wid] = sq; }
    __syncthreads();
    s = rs[0] + rs[1]; sq = rq[0] + rq[1];
    float mu   = s * (1.0f / 512.0f);
    float var  = sq * (1.0f / 512.0f) - mu * mu;
    float rstd = rsqrtf(var + 1e-5f);
    float4 gv = ((const float4*)g)[t];
    float4 bv = ((const float4*)bb)[t];
    float4 y = { (xv.x - mu) * rstd * gv.x + bv.x,
                 (xv.y - mu) * rstd * gv.y + bv.y,
                 (xv.z - mu) * rstd * gv.z + bv.z,
                 (xv.w - mu) * rstd * gv.w + bv.w };
    if (WF32) ((float4*)of)[(long)row * 128 + t] = y;
    bf16x4 yb = { (bf16)y.x, (bf16)y.y, (bf16)y.z, (bf16)y.w };
    ((bf16x4*)ob)[(long)row * 128 + t] = yb;
}

// ---------------------------------------------------------------- causal softmax
__global__ void softmax_causal(const float* __restrict__ sc, bf16* __restrict__ pr) {
    int row = blockIdx.x;            // 8192
    int z = row >> 11, q = row & 2047;
    const float* srow = sc + ((long)z * 2048 + q) * 2048;
    bf16*        prow = pr + ((long)z * 2048 + q) * 2048;
    int t = threadIdx.x;             // 256, each handles 8 cols
    float v[8];
    int c0 = t * 8;
    if (t <= (q >> 3)) {
        float4 v0 = ((const float4*)srow)[t * 2];
        float4 v1 = ((const float4*)srow)[t * 2 + 1];
        v[0] = v0.x; v[1] = v0.y; v[2] = v0.z; v[3] = v0.w;
        v[4] = v1.x; v[5] = v1.y; v[6] = v1.z; v[7] = v1.w;
    } else {
        #pragma unroll
        for (int j = 0; j < 8; j++) v[j] = -1e30f;
    }
    float mx = -1e30f;
    #pragma unroll
    for (int j = 0; j < 8; j++) {
        if (c0 + j > q) v[j] = -1e30f;
        mx = fmaxf(mx, v[j]);
    }
    int lane = t & 63, wid = t >> 6;
    #pragma unroll
    for (int o = 32; o > 0; o >>= 1) mx = fmaxf(mx, __shfl_xor(mx, o));
    __shared__ float redm[4], reds[4];
    if (lane == 0) redm[wid] = mx;
    __syncthreads();
    mx = fmaxf(fmaxf(redm[0], redm[1]), fmaxf(redm[2], redm[3]));
    float p[8]; float sum = 0.f;
    #pragma unroll
    for (int j = 0; j < 8; j++) {
        p[j] = (c0 + j <= q) ? __expf(v[j] - mx) : 0.f;
        sum += p[j];
    }
    #pragma unroll
    for (int o = 32; o > 0; o >>= 1) sum += __shfl_xor(sum, o);
    if (lane == 0) reds[wid] = sum;
    __syncthreads();
    sum = reds[0] + reds[1] + reds[2] + reds[3];
    float inv = 1.0f / sum;
    int wlim = ((q >> 7) + 1) * 128;             // causal 128-block boundary
    if (c0 < wlim) {
        bf16x8 o;
        #pragma unroll
        for (int j = 0; j < 8; j++) o[j] = (bf16)(p[j] * inv);
        *(bf16x8*)&prow[c0] = o;
    }
}

// ---------------------------------------------------------------- epilogue tags
enum { EPI_F32 = 0, EPI_BF16 = 1, EPI_VT = 2, EPI_BIAS_RELU_BF16 = 3, EPI_BIAS_F32 = 4,
       EPI_QKV = 5 };
enum { ZB_BATCH = 0 };

// ---------------------------------------------------------------- 128^2 GEMM (proven)
template<int EPI, bool CAUSAL_SKIP, bool CAUSAL_K, bool XCD, int ZMODE>
__global__ __launch_bounds__(256)
void gemm_bt(const bf16* __restrict__ A, const bf16* __restrict__ B,
             float* __restrict__ Cf, bf16* __restrict__ Cb,
             const float* __restrict__ bias, float scale,
             int M, int N, int K, int Krow, long sA, long sB, long sC) {
    int br, bc;
    if (XCD) {
        int nwg = gridDim.x * gridDim.y;         // caller ensures %8==0
        int lin = blockIdx.y * gridDim.x + blockIdx.x;
        lin = (lin & 7) * (nwg >> 3) + (lin >> 3);
        br = lin / gridDim.x; bc = lin - br * gridDim.x;
    } else { br = blockIdx.y; bc = blockIdx.x; }
    int z = blockIdx.z;
    A += (long)z * sA; B += (long)z * sB; Cf += (long)z * sC;
    if (CAUSAL_SKIP && bc > br) return;
    int Kext = CAUSAL_K ? min(K, (br + 1) * 128) : K;
    __shared__ bf16 As[128 * 64];
    __shared__ bf16 Bs[128 * 64];
    int tid = threadIdx.x;
    int lane = tid & 63, wid = tid >> 6;
    int wm = (wid >> 1) * 64, wn = (wid & 1) * 64;
    f32x4 acc[4][4] = {};
    int rowA0 = br * 128, colB0 = bc * 128;
    int rsub = lane >> 3;
    int csub = ((lane & 7) ^ rsub) * 8;            // pre-swizzled source col
    int rdsw = (lane & 7) * 8;                     // read-side XOR
    for (int kt = 0; kt < Kext; kt += 64) {
        const bf16* Ag = A + (long)rowA0 * Krow + kt;
        const bf16* Bg = B + (long)colB0 * Krow + kt;
        #pragma unroll
        for (int i = 0; i < 4; i++) {
            int seg = wid * 4 + i;
            int r = seg * 8 + rsub;
            gload_lds16(&Ag[(long)r * Krow + csub], &As[seg * 512]);
            gload_lds16(&Bg[(long)r * Krow + csub], &Bs[seg * 512]);
        }
        __syncthreads();
        #pragma unroll
        for (int kk = 0; kk < 2; kk++) {
            bf16x8 af[4], bfr[4];
            int ko = (kk * 32 + (lane >> 4) * 8) ^ rdsw;
            #pragma unroll
            for (int m = 0; m < 4; m++) af[m]  = *(const bf16x8*)&As[(wm + m * 16 + (lane & 15)) * 64 + ko];
            #pragma unroll
            for (int n = 0; n < 4; n++) bfr[n] = *(const bf16x8*)&Bs[(wn + n * 16 + (lane & 15)) * 64 + ko];
            #pragma unroll
            for (int m = 0; m < 4; m++)
                #pragma unroll
                for (int n = 0; n < 4; n++)
                    acc[m][n] = __builtin_amdgcn_mfma_f32_16x16x32_bf16(af[m], bfr[n], acc[m][n], 0, 0, 0);
        }
        __syncthreads();
    }
    #pragma unroll
    for (int m = 0; m < 4; m++) {
        #pragma unroll
        for (int n = 0; n < 4; n++) {
            #pragma unroll
            for (int j = 0; j < 4; j++) {
                int row = rowA0 + wm + m * 16 + (lane >> 4) * 4 + j;
                int col = colB0 + wn + n * 16 + (lane & 15);
                float v = acc[m][n][j];
                if (EPI == EPI_F32) {
                    Cf[(long)row * N + col] = v;        // z-offset already applied
                } else if (EPI == EPI_BF16) {
                    Cb[(long)row * N + col] = (bf16)(v * scale);
                } else if (EPI == EPI_VT) {
                    int b = row >> 11, k = row & 2047;
                    Cb[((long)b * 512 + col) * 2048 + k] = (bf16)v;
                } else if (EPI == EPI_BIAS_RELU_BF16) {
                    float y = fmaxf(v + bias[col], 0.0f);
                    Cb[(long)row * N + col] = (bf16)y;
                } else if (EPI == EPI_BIAS_F32) {
                    Cf[(long)row * N + col] = v + bias[col];
                }
            }
        }
    }
}

// ---------------------------------------------------------------- 256^2 deep-pipeline GEMM (BK=64)
// BANDW > 0: column-band tile order. Output processed in bands of BANDW
// col-tiles; within a band, row-major sweep. Shrinks the B-panel reuse
// distance from (all cols) to BANDW panels so B stays L2/L3-resident against
// the streaming C-write eviction pressure, while concurrent blocks still
// write same-rows/adjacent-cols (the DRAM-friendly pattern CMAJOR broke).
// Caller must ensure gridDim.x % BANDW == 0.
template<int EPI, bool XCD, bool CSKIP, int BANDW, int NT>
__global__ __launch_bounds__(512)
void gemm256(const bf16* __restrict__ A, const bf16* __restrict__ B,
             float* __restrict__ Cf, bf16* __restrict__ Cb,
             const float* __restrict__ bias, int N, int K,
             long sA, long sB, long sC) {
    int br, bc;
    if (XCD) {
        int nwg = gridDim.x * gridDim.y;          // caller ensures %8==0
        int lin = blockIdx.y * gridDim.x + blockIdx.x;
        lin = (lin & 7) * (nwg >> 3) + (lin >> 3);
        if (BANDW > 0) {
            int per = BANDW * gridDim.y;          // blocks per band
            int band = lin / per, w2 = lin - band * per;
            br = w2 / BANDW; bc = band * BANDW + (w2 - br * BANDW);
        } else {
            br = lin / gridDim.x; bc = lin - br * gridDim.x;
        }
    } else { br = blockIdx.y; bc = blockIdx.x; }
    if (CSKIP && bc > br) return;                 // causal skip at 256-tile granularity
    int z = blockIdx.z;
    A  += (long)z * sA;
    B  += (long)z * sB;
    Cf += (long)z * sC;
    __shared__ bf16 lds[2][2][256 * 64];          // [buf][A/B] = 128 KiB
    int tid = threadIdx.x;
    int lane = tid & 63, wid = tid >> 6;
    int wm2 = wid >> 2, wn4 = wid & 3;
    long rowA0 = (long)br * 256, colB0 = (long)bc * 256;
    int rsub = lane >> 3;
    int csw  = ((lane & 7) ^ rsub) * 8;           // pre-swizzled source col
    int l15 = lane & 15;
    int rdxor = (lane & 7) << 3;
    int kbase = (lane >> 4) * 8;
    const bf16* Abase = A + rowA0 * K;
    const bf16* Bbase = B + colB0 * K;
    f32x4 acc[8][4] = {};

    auto stage = [&](int t) {
        int buf = t & 1;
        const bf16* Ag = Abase + t * 64;
        const bf16* Bg = Bbase + t * 64;
        #pragma unroll
        for (int i = 0; i < 4; i++) {
            int seg = wid * 4 + i;                // 0..31
            long r = seg * 8 + rsub;
            gload_lds16(&Ag[r * K + csw], &lds[buf][0][seg * 512]);
        }
        #pragma unroll
        for (int i = 0; i < 4; i++) {
            int seg = wid * 4 + i;
            long r = seg * 8 + rsub;
            gload_lds16(&Bg[r * K + csw], &lds[buf][1][seg * 512]);
        }
    };

    stage(0);
    stage(1);

    for (int t = 0; t < NT; t++) {
        int buf = t & 1;
        if (t == NT - 1) asm volatile("s_waitcnt vmcnt(0)" ::: "memory");
        else             asm volatile("s_waitcnt vmcnt(8)" ::: "memory");
        __builtin_amdgcn_s_barrier();             // everyone's tile-t data visible
        const bf16* As = lds[buf][0];
        const bf16* Bs = lds[buf][1];
        bf16x8 bfr[2][4], af[2][4];
        #pragma unroll
        for (int kk = 0; kk < 2; kk++)
            #pragma unroll
            for (int n = 0; n < 4; n++) {
                int r = wn4 * 64 + n * 16 + l15;
                bfr[kk][n] = *(const bf16x8*)&Bs[r * 64 + ((kk * 32 + kbase) ^ rdxor)];
            }
        #pragma unroll
        for (int kk = 0; kk < 2; kk++)
            #pragma unroll
            for (int m = 0; m < 4; m++) {
                int r = wm2 * 128 + m * 16 + l15;
                af[kk][m] = *(const bf16x8*)&As[r * 64 + ((kk * 32 + kbase) ^ rdxor)];
            }
        __builtin_amdgcn_s_setprio(1);
        #pragma unroll
        for (int kk = 0; kk < 2; kk++)
            #pragma unroll
            for (int m = 0; m < 4; m++)
                #pragma unroll
                for (int n = 0; n < 4; n++)
                    acc[m][n] = __builtin_amdgcn_mfma_f32_16x16x32_bf16(af[kk][m], bfr[kk][n], acc[m][n], 0, 0, 0);
        __builtin_amdgcn_s_setprio(0);
        // second half of A rows
        #pragma unroll
        for (int kk = 0; kk < 2; kk++)
            #pragma unroll
            for (int m = 0; m < 4; m++) {
                int r = wm2 * 128 + 64 + m * 16 + l15;
                af[kk][m] = *(const bf16x8*)&As[r * 64 + ((kk * 32 + kbase) ^ rdxor)];
            }
        asm volatile("s_waitcnt lgkmcnt(0)" ::: "memory"); // all my buf reads done
        __builtin_amdgcn_sched_barrier(0);
        __builtin_amdgcn_s_barrier();             // ALL waves done reading buf
        if (t + 2 < NT) stage(t + 2);             // overwrite buf; flies across iters
        __builtin_amdgcn_s_setprio(1);
        #pragma unroll
        for (int kk = 0; kk < 2; kk++)
            #pragma unroll
            for (int m = 0; m < 4; m++)
                #pragma unroll
                for (int n = 0; n < 4; n++)
                    acc[4 + m][n] = __builtin_amdgcn_mfma_f32_16x16x32_bf16(af[kk][m], bfr[kk][n], acc[4 + m][n], 0, 0, 0);
        __builtin_amdgcn_s_setprio(0);
    }

    if constexpr (EPI == EPI_QKV) {
        // N=1536; 256-col panels are block-uniform: 0-1=Q, 2-3=K, 4-5=V.
        int region = (int)(colB0 >> 9);           // 0=Q, 1=K, 2=V
        if (region < 2) {
            bf16* dst = Cb + (long)region * (8192L * 512);
            int cb = ((int)colB0 & 511) + wn4 * 64;
            #pragma unroll
            for (int m = 0; m < 8; m++)
                #pragma unroll
                for (int n = 0; n < 4; n++)
                    #pragma unroll
                    for (int j = 0; j < 4; j++) {
                        long row = rowA0 + wm2 * 128 + m * 16 + (lane >> 4) * 4 + j;
                        int c = cb + n * 16 + l15;
                        dst[row * 512 + c] = (bf16)acc[m][n][j];
                    }
        } else {
            bf16* vtb = Cb + 2L * 8192 * 512;
            int cb = ((int)colB0 - 1024) + wn4 * 64;
            #pragma unroll
            for (int m = 0; m < 8; m++)
                #pragma unroll
                for (int n = 0; n < 4; n++) {
                    long k0 = rowA0 + wm2 * 128 + m * 16 + (lane >> 4) * 4;
                    long b = k0 >> 11, k = k0 & 2047;
                    int c = cb + n * 16 + l15;
                    bf16x4 pk = { (bf16)acc[m][n][0], (bf16)acc[m][n][1],
                                  (bf16)acc[m][n][2], (bf16)acc[m][n][3] };
                    *(bf16x4*)&vtb[(b * 512 + c) * 2048 + k] = pk;
                }
        }
    } else {
        #pragma unroll
        for (int m = 0; m < 8; m++) {
            #pragma unroll
            for (int n = 0; n < 4; n++) {
                #pragma unroll
                for (int j = 0; j < 4; j++) {
                    long row = rowA0 + wm2 * 128 + m * 16 + (lane >> 4) * 4 + j;
                    long col = colB0 + wn4 * 64 + n * 16 + l15;
                    float v = acc[m][n][j];
                    if (EPI == EPI_BIAS_F32) {
                        Cf[row * N + col] = v + bias[col];
                    } else if (EPI == EPI_BIAS_RELU_BF16) {
                        Cb[row * N + col] = (bf16)fmaxf(v + bias[col], 0.0f);
                    } else if (EPI == EPI_F32) {
                        Cf[row * N + col] = v;
                    }
                }
            }
        }
    }
}

// ---------------------------------------------------------------- launch
extern "C" void kernel_launch(void* const* d_in, const int* in_sizes, int n_in,
                              void* d_out, int out_size, void* d_ws, size_t ws_size,
                              hipStream_t stream) {
    const int*   x       = (const int*)d_in[0];
    const float* word_emb = (const float*)d_in[1];
    const float* pos_emb  = (const float*)d_in[2];
    const float* Wq = (const float*)d_in[3];
    const float* Wk = (const float*)d_in[4];
    const float* Wv = (const float*)d_in[5];
    const float* g1 = (const float*)d_in[6];
    const float* b1 = (const float*)d_in[7];
    const float* w_ffn1 = (const float*)d_in[8];
    const float* b_ffn1 = (const float*)d_in[9];
    const float* w_ffn2 = (const float*)d_in[10];
    const float* b_ffn2 = (const float*)d_in[11];
    const float* g2 = (const float*)d_in[12];
    const float* b2 = (const float*)d_in[13];
    const float* w_vocab = (const float*)d_in[14];
    const float* b_vocab = (const float*)d_in[15];
    float* out = (float*)d_out;

    char* w = (char*)d_ws;
    auto alloc = [&](size_t bytes) { char* p = w; w += (bytes + 255) & ~255ULL; return p; };
    // NOTE: wqb/wkb/wvb must stay contiguous ([1536 x 512] fused weight);
    //       qb/kb/vt must stay contiguous (EPI_QKV writes all three off qb).
    bf16* wqb   = (bf16*)alloc(512 * 512 * 2);
    bf16* wkb   = (bf16*)alloc(512 * 512 * 2);
    bf16* wvb   = (bf16*)alloc(512 * 512 * 2);
    bf16* w1b   = (bf16*)alloc(2048 * 512 * 2);
    bf16* w2b   = (bf16*)alloc(512 * 2048 * 2);
    bf16* wvocb = (bf16*)alloc((size_t)32000 * 512 * 2);
    float* embf = (float*)alloc((size_t)8192 * 512 * 4);
    bf16* embb  = (bf16*)alloc((size_t)8192 * 512 * 2);   // also final_b (aliased)
    bf16* qb    = (bf16*)alloc((size_t)8192 * 512 * 2);
    bf16* kb    = (bf16*)alloc((size_t)8192 * 512 * 2);   // also out1_b (aliased)
    bf16* vt    = (bf16*)alloc((size_t)8192 * 512 * 2);
    float* scores = (float*)alloc((size_t)4 * 2048 * 2048 * 4); // also ffn1_b (aliased)
    bf16* probs = (bf16*)alloc((size_t)4 * 2048 * 2048 * 2);
    float* ctx  = (float*)alloc((size_t)8192 * 512 * 4);
    float* out1f = (float*)alloc((size_t)8192 * 512 * 4);
    float* ffn2f = (float*)alloc((size_t)8192 * 512 * 4);
    bf16* ffn1b = (bf16*)scores;   // alias: scores dead after softmax
    bf16* out1b = kb;              // alias: kb dead after scores GEMM
    bf16* finalb = embb;           // alias: embb dead after QKV GEMM

    const float qscale = 0.044194173824159216f; // 1/sqrt(512)

    // one launch converts all six weight tensors (Wq pre-scaled by 1/sqrt(d_k))
    CvtArgs ca;
    ca.src[0] = Wq;      ca.dst[0] = wqb;   ca.n4[0] = 512 * 512 / 4;          ca.scale[0] = qscale;
    ca.src[1] = Wk;      ca.dst[1] = wkb;   ca.n4[1] = 512 * 512 / 4;          ca.scale[1] = 1.0f;
    ca.src[2] = Wv;      ca.dst[2] = wvb;   ca.n4[2] = 512 * 512 / 4;          ca.scale[2] = 1.0f;
    ca.src[3] = w_ffn1;  ca.dst[3] = w1b;   ca.n4[3] = 2048 * 512 / 4;         ca.scale[3] = 1.0f;
    ca.src[4] = w_ffn2;  ca.dst[4] = w2b;   ca.n4[4] = 512 * 2048 / 4;         ca.scale[4] = 1.0f;
    ca.src[5] = w_vocab; ca.dst[5] = wvocb; ca.n4[5] = (long)32000 * 512 / 4;  ca.scale[5] = 1.0f;
    cvt_all<<<dim3(256, 6), 256, 0, stream>>>(ca);

    embed_kernel<<<8192, 128, 0, stream>>>(x, word_emb, pos_emb, embf, embb);

    // fused Q|K|V projection: emb[8192x512] @ Wqkv^T[1536x512] -> qb,kb,vt
    gemm256<EPI_QKV, true, false, 0, 8><<<dim3(6, 32, 1), 512, 0, stream>>>(
        embb, wqb, nullptr, qb, nullptr, 1536, 512, 0, 0, 0);

    // scores = Q @ K^T (batched 256^2 deep pipeline, causal block skip)
    gemm256<EPI_F32, true, true, 0, 8><<<dim3(8, 8, 4), 512, 0, stream>>>(
        qb, kb, scores, nullptr, nullptr, 2048, 512,
        (long)2048 * 512, (long)2048 * 512, (long)2048 * 2048);

    softmax_causal<<<8192, 256, 0, stream>>>(scores, probs);

    // context = P @ V (B operand = V^T, batched, causal K-limit)
    gemm_bt<EPI_F32, false, true, false, ZB_BATCH><<<dim3(4, 16, 4), 256, 0, stream>>>(
        probs, vt, ctx, nullptr, nullptr, 1.0f, 2048, 512, 2048, 2048,
        (long)2048 * 2048, (long)512 * 2048, (long)2048 * 512);

    ln_kernel<true><<<8192, 128, 0, stream>>>(embf, ctx, g1, b1, out1f, out1b);

    // ffn1 = relu(out1 @ W1^T + b1)  -- 256^2 deep pipeline
    gemm256<EPI_BIAS_RELU_BF16, true, false, 0, 8><<<dim3(8, 32, 1), 512, 0, stream>>>(
        out1b, w1b, nullptr, ffn1b, b_ffn1, 2048, 512, 0, 0, 0);

    // ffn2 = ffn1 @ W2^T + b2  (N=512 -> keep 128^2)
    gemm_bt<EPI_BIAS_F32, false, false, false, ZB_BATCH><<<dim3(4, 64, 1), 256, 0, stream>>>(
        ffn1b, w2b, ffn2f, nullptr, b_ffn2, 1.0f, 8192, 512, 2048, 2048, 0, 0, 0);

    ln_kernel<false><<<8192, 128, 0, stream>>>(out1f, ffn2f, g2, b2, nullptr, finalb);

    // logits = final @ w_vocab^T + b_vocab  -- BK=64 deep pipeline, 5 column
    // bands of 25 col-tiles (125 = 5*25): B-panel reuse distance ~13 MB (L3-
    // resident vs the 1 GB write stream), writes stay row-major adjacent.
    gemm256<EPI_BIAS_F32, true, false, 25, 8><<<dim3(125, 32, 1), 512, 0, stream>>>(
        finalb, wvocb, out, nullptr, b_vocab, 32000, 512, 0, 0, 0);
}

// Round 7
// 582.012 us; speedup vs baseline: 1.2340x; 1.0818x over previous
//
#include <hip/hip_runtime.h>
#include <hip/hip_bf16.h>

typedef __bf16 bf16;
typedef __attribute__((ext_vector_type(4))) __bf16 bf16x4;
typedef __attribute__((ext_vector_type(8))) __bf16 bf16x8;
typedef __attribute__((ext_vector_type(4))) float f32x4;

__device__ inline void gload_lds16(const bf16* g, bf16* l) {
    __builtin_amdgcn_global_load_lds(
        (const __attribute__((address_space(1))) void*)g,
        (__attribute__((address_space(3))) void*)l, 16, 0, 0);
}

// ---------------------------------------------------------------- fused conversions
struct CvtArgs {
    const float* src[6];
    bf16* dst[6];
    long n4[6];
    float scale[6];
};
__global__ void cvt_all(CvtArgs a) {
    int j = blockIdx.y;
    const float* __restrict__ src = a.src[j];
    bf16* __restrict__ dst = a.dst[j];
    long n4 = a.n4[j];
    float sc = a.scale[j];
    long i = (long)blockIdx.x * blockDim.x + threadIdx.x;
    long stride = (long)gridDim.x * blockDim.x;
    for (; i < n4; i += stride) {
        float4 v = ((const float4*)src)[i];
        bf16x4 o = { (bf16)(v.x * sc), (bf16)(v.y * sc), (bf16)(v.z * sc), (bf16)(v.w * sc) };
        ((bf16x4*)dst)[i] = o;
    }
}

// ---------------------------------------------------------------- embedding
__global__ void embed_kernel(const int* __restrict__ x, const float* __restrict__ we,
                             const float* __restrict__ pe, float* __restrict__ emb_f,
                             bf16* __restrict__ emb_b) {
    int row = blockIdx.x;            // 0..8191  (b*2048 + s)
    int c   = threadIdx.x;           // 0..127
    int tok = x[row];
    int s   = row & 2047;
    float4 w = ((const float4*)we)[(long)tok * 128 + c];
    float4 p = ((const float4*)pe)[(long)s * 128 + c];
    float4 e = { w.x + p.x, w.y + p.y, w.z + p.z, w.w + p.w };
    ((float4*)emb_f)[(long)row * 128 + c] = e;
    bf16x4 eb = { (bf16)e.x, (bf16)e.y, (bf16)e.z, (bf16)e.w };
    ((bf16x4*)emb_b)[(long)row * 128 + c] = eb;
}

// ---------------------------------------------------------------- layernorm
template<bool WF32>
__global__ void ln_kernel(const float* __restrict__ a, const float* __restrict__ bres,
                          const float* __restrict__ g, const float* __restrict__ bb,
                          float* __restrict__ of, bf16* __restrict__ ob) {
    int row = blockIdx.x;            // 8192
    int t   = threadIdx.x;           // 128
    float4 xa = ((const float4*)a)[(long)row * 128 + t];
    float4 xb = ((const float4*)bres)[(long)row * 128 + t];
    float4 xv = { xa.x + xb.x, xa.y + xb.y, xa.z + xb.z, xa.w + xb.w };
    float s  = xv.x + xv.y + xv.z + xv.w;
    float sq = xv.x * xv.x + xv.y * xv.y + xv.z * xv.z + xv.w * xv.w;
    #pragma unroll
    for (int o = 32; o > 0; o >>= 1) {
        s  += __shfl_xor(s, o);
        sq += __shfl_xor(sq, o);
    }
    __shared__ float rs[2], rq[2];
    int wid = t >> 6;
    if ((t & 63) == 0) { rs[wid] = s; rq[wid] = sq; }
    __syncthreads();
    s = rs[0] + rs[1]; sq = rq[0] + rq[1];
    float mu   = s * (1.0f / 512.0f);
    float var  = sq * (1.0f / 512.0f) - mu * mu;
    float rstd = rsqrtf(var + 1e-5f);
    float4 gv = ((const float4*)g)[t];
    float4 bv = ((const float4*)bb)[t];
    float4 y = { (xv.x - mu) * rstd * gv.x + bv.x,
                 (xv.y - mu) * rstd * gv.y + bv.y,
                 (xv.z - mu) * rstd * gv.z + bv.z,
                 (xv.w - mu) * rstd * gv.w + bv.w };
    if (WF32) ((float4*)of)[(long)row * 128 + t] = y;
    bf16x4 yb = { (bf16)y.x, (bf16)y.y, (bf16)y.z, (bf16)y.w };
    ((bf16x4*)ob)[(long)row * 128 + t] = yb;
}

// ---------------------------------------------------------------- causal softmax
__global__ void softmax_causal(const float* __restrict__ sc, bf16* __restrict__ pr) {
    int row = blockIdx.x;            // 8192
    int z = row >> 11, q = row & 2047;
    const float* srow = sc + ((long)z * 2048 + q) * 2048;
    bf16*        prow = pr + ((long)z * 2048 + q) * 2048;
    int t = threadIdx.x;             // 256, each handles 8 cols
    float v[8];
    int c0 = t * 8;
    if (t <= (q >> 3)) {
        float4 v0 = ((const float4*)srow)[t * 2];
        float4 v1 = ((const float4*)srow)[t * 2 + 1];
        v[0] = v0.x; v[1] = v0.y; v[2] = v0.z; v[3] = v0.w;
        v[4] = v1.x; v[5] = v1.y; v[6] = v1.z; v[7] = v1.w;
    } else {
        #pragma unroll
        for (int j = 0; j < 8; j++) v[j] = -1e30f;
    }
    float mx = -1e30f;
    #pragma unroll
    for (int j = 0; j < 8; j++) {
        if (c0 + j > q) v[j] = -1e30f;
        mx = fmaxf(mx, v[j]);
    }
    int lane = t & 63, wid = t >> 6;
    #pragma unroll
    for (int o = 32; o > 0; o >>= 1) mx = fmaxf(mx, __shfl_xor(mx, o));
    __shared__ float redm[4], reds[4];
    if (lane == 0) redm[wid] = mx;
    __syncthreads();
    mx = fmaxf(fmaxf(redm[0], redm[1]), fmaxf(redm[2], redm[3]));
    float p[8]; float sum = 0.f;
    #pragma unroll
    for (int j = 0; j < 8; j++) {
        p[j] = (c0 + j <= q) ? __expf(v[j] - mx) : 0.f;
        sum += p[j];
    }
    #pragma unroll
    for (int o = 32; o > 0; o >>= 1) sum += __shfl_xor(sum, o);
    if (lane == 0) reds[wid] = sum;
    __syncthreads();
    sum = reds[0] + reds[1] + reds[2] + reds[3];
    float inv = 1.0f / sum;
    int wlim = ((q >> 7) + 1) * 128;             // causal 128-block boundary
    if (c0 < wlim) {
        bf16x8 o;
        #pragma unroll
        for (int j = 0; j < 8; j++) o[j] = (bf16)(p[j] * inv);
        *(bf16x8*)&prow[c0] = o;
    }
}

// ---------------------------------------------------------------- epilogue tags
enum { EPI_F32 = 0, EPI_BF16 = 1, EPI_VT = 2, EPI_BIAS_RELU_BF16 = 3, EPI_BIAS_F32 = 4,
       EPI_QKV = 5, EPI_BIAS_F32_NT = 6 };
enum { ZB_BATCH = 0 };

// ---------------------------------------------------------------- 128^2 GEMM (proven)
template<int EPI, bool CAUSAL_SKIP, bool CAUSAL_K, bool XCD, int ZMODE>
__global__ __launch_bounds__(256)
void gemm_bt(const bf16* __restrict__ A, const bf16* __restrict__ B,
             float* __restrict__ Cf, bf16* __restrict__ Cb,
             const float* __restrict__ bias, float scale,
             int M, int N, int K, int Krow, long sA, long sB, long sC) {
    int br, bc;
    if (XCD) {
        int nwg = gridDim.x * gridDim.y;         // caller ensures %8==0
        int lin = blockIdx.y * gridDim.x + blockIdx.x;
        lin = (lin & 7) * (nwg >> 3) + (lin >> 3);
        br = lin / gridDim.x; bc = lin - br * gridDim.x;
    } else { br = blockIdx.y; bc = blockIdx.x; }
    int z = blockIdx.z;
    A += (long)z * sA; B += (long)z * sB; Cf += (long)z * sC;
    if (CAUSAL_SKIP && bc > br) return;
    int Kext = CAUSAL_K ? min(K, (br + 1) * 128) : K;
    __shared__ bf16 As[128 * 64];
    __shared__ bf16 Bs[128 * 64];
    int tid = threadIdx.x;
    int lane = tid & 63, wid = tid >> 6;
    int wm = (wid >> 1) * 64, wn = (wid & 1) * 64;
    f32x4 acc[4][4] = {};
    int rowA0 = br * 128, colB0 = bc * 128;
    int rsub = lane >> 3;
    int csub = ((lane & 7) ^ rsub) * 8;            // pre-swizzled source col
    int rdsw = (lane & 7) * 8;                     // read-side XOR
    for (int kt = 0; kt < Kext; kt += 64) {
        const bf16* Ag = A + (long)rowA0 * Krow + kt;
        const bf16* Bg = B + (long)colB0 * Krow + kt;
        #pragma unroll
        for (int i = 0; i < 4; i++) {
            int seg = wid * 4 + i;
            int r = seg * 8 + rsub;
            gload_lds16(&Ag[(long)r * Krow + csub], &As[seg * 512]);
            gload_lds16(&Bg[(long)r * Krow + csub], &Bs[seg * 512]);
        }
        __syncthreads();
        #pragma unroll
        for (int kk = 0; kk < 2; kk++) {
            bf16x8 af[4], bfr[4];
            int ko = (kk * 32 + (lane >> 4) * 8) ^ rdsw;
            #pragma unroll
            for (int m = 0; m < 4; m++) af[m]  = *(const bf16x8*)&As[(wm + m * 16 + (lane & 15)) * 64 + ko];
            #pragma unroll
            for (int n = 0; n < 4; n++) bfr[n] = *(const bf16x8*)&Bs[(wn + n * 16 + (lane & 15)) * 64 + ko];
            #pragma unroll
            for (int m = 0; m < 4; m++)
                #pragma unroll
                for (int n = 0; n < 4; n++)
                    acc[m][n] = __builtin_amdgcn_mfma_f32_16x16x32_bf16(af[m], bfr[n], acc[m][n], 0, 0, 0);
        }
        __syncthreads();
    }
    #pragma unroll
    for (int m = 0; m < 4; m++) {
        #pragma unroll
        for (int n = 0; n < 4; n++) {
            #pragma unroll
            for (int j = 0; j < 4; j++) {
                int row = rowA0 + wm + m * 16 + (lane >> 4) * 4 + j;
                int col = colB0 + wn + n * 16 + (lane & 15);
                float v = acc[m][n][j];
                if (EPI == EPI_F32) {
                    Cf[(long)row * N + col] = v;        // z-offset already applied
                } else if (EPI == EPI_BF16) {
                    Cb[(long)row * N + col] = (bf16)(v * scale);
                } else if (EPI == EPI_VT) {
                    int b = row >> 11, k = row & 2047;
                    Cb[((long)b * 512 + col) * 2048 + k] = (bf16)v;
                } else if (EPI == EPI_BIAS_RELU_BF16) {
                    float y = fmaxf(v + bias[col], 0.0f);
                    Cb[(long)row * N + col] = (bf16)y;
                } else if (EPI == EPI_BIAS_F32) {
                    Cf[(long)row * N + col] = v + bias[col];
                }
            }
        }
    }
}

// ---------------------------------------------------------------- 256^2 deep-pipeline GEMM (BK=64)
// BANDW > 0: column-band tile order. Output processed in bands of BANDW
// col-tiles; within a band, row-major sweep. Shrinks the B-panel reuse
// distance so B stays L2-resident against the streaming C-write eviction
// pressure. Caller must ensure gridDim.x % BANDW == 0.
template<int EPI, bool XCD, bool CSKIP, int BANDW, int NT>
__global__ __launch_bounds__(512)
void gemm256(const bf16* __restrict__ A, const bf16* __restrict__ B,
             float* __restrict__ Cf, bf16* __restrict__ Cb,
             const float* __restrict__ bias, int N, int K,
             long sA, long sB, long sC) {
    int br, bc;
    if (XCD) {
        int nwg = gridDim.x * gridDim.y;          // caller ensures %8==0
        int lin = blockIdx.y * gridDim.x + blockIdx.x;
        lin = (lin & 7) * (nwg >> 3) + (lin >> 3);
        if (BANDW > 0) {
            int per = BANDW * gridDim.y;          // blocks per band
            int band = lin / per, w2 = lin - band * per;
            br = w2 / BANDW; bc = band * BANDW + (w2 - br * BANDW);
        } else {
            br = lin / gridDim.x; bc = lin - br * gridDim.x;
        }
    } else { br = blockIdx.y; bc = blockIdx.x; }
    if (CSKIP && bc > br) return;                 // causal skip at 256-tile granularity
    int z = blockIdx.z;
    A  += (long)z * sA;
    B  += (long)z * sB;
    Cf += (long)z * sC;
    __shared__ bf16 lds[2][2][256 * 64];          // [buf][A/B] = 128 KiB
    int tid = threadIdx.x;
    int lane = tid & 63, wid = tid >> 6;
    int wm2 = wid >> 2, wn4 = wid & 3;
    long rowA0 = (long)br * 256, colB0 = (long)bc * 256;
    int rsub = lane >> 3;
    int csw  = ((lane & 7) ^ rsub) * 8;           // pre-swizzled source col
    int l15 = lane & 15;
    int rdxor = (lane & 7) << 3;
    int kbase = (lane >> 4) * 8;
    const bf16* Abase = A + rowA0 * K;
    const bf16* Bbase = B + colB0 * K;
    f32x4 acc[8][4] = {};

    auto stage = [&](int t) {
        int buf = t & 1;
        const bf16* Ag = Abase + t * 64;
        const bf16* Bg = Bbase + t * 64;
        #pragma unroll
        for (int i = 0; i < 4; i++) {
            int seg = wid * 4 + i;                // 0..31
            long r = seg * 8 + rsub;
            gload_lds16(&Ag[r * K + csw], &lds[buf][0][seg * 512]);
        }
        #pragma unroll
        for (int i = 0; i < 4; i++) {
            int seg = wid * 4 + i;
            long r = seg * 8 + rsub;
            gload_lds16(&Bg[r * K + csw], &lds[buf][1][seg * 512]);
        }
    };

    stage(0);
    stage(1);

    for (int t = 0; t < NT; t++) {
        int buf = t & 1;
        if (t == NT - 1) asm volatile("s_waitcnt vmcnt(0)" ::: "memory");
        else             asm volatile("s_waitcnt vmcnt(8)" ::: "memory");
        __builtin_amdgcn_s_barrier();             // everyone's tile-t data visible
        const bf16* As = lds[buf][0];
        const bf16* Bs = lds[buf][1];
        bf16x8 bfr[2][4], af[2][4];
        #pragma unroll
        for (int kk = 0; kk < 2; kk++)
            #pragma unroll
            for (int n = 0; n < 4; n++) {
                int r = wn4 * 64 + n * 16 + l15;
                bfr[kk][n] = *(const bf16x8*)&Bs[r * 64 + ((kk * 32 + kbase) ^ rdxor)];
            }
        #pragma unroll
        for (int kk = 0; kk < 2; kk++)
            #pragma unroll
            for (int m = 0; m < 4; m++) {
                int r = wm2 * 128 + m * 16 + l15;
                af[kk][m] = *(const bf16x8*)&As[r * 64 + ((kk * 32 + kbase) ^ rdxor)];
            }
        __builtin_amdgcn_s_setprio(1);
        #pragma unroll
        for (int kk = 0; kk < 2; kk++)
            #pragma unroll
            for (int m = 0; m < 4; m++)
                #pragma unroll
                for (int n = 0; n < 4; n++)
                    acc[m][n] = __builtin_amdgcn_mfma_f32_16x16x32_bf16(af[kk][m], bfr[kk][n], acc[m][n], 0, 0, 0);
        __builtin_amdgcn_s_setprio(0);
        // second half of A rows
        #pragma unroll
        for (int kk = 0; kk < 2; kk++)
            #pragma unroll
            for (int m = 0; m < 4; m++) {
                int r = wm2 * 128 + 64 + m * 16 + l15;
                af[kk][m] = *(const bf16x8*)&As[r * 64 + ((kk * 32 + kbase) ^ rdxor)];
            }
        asm volatile("s_waitcnt lgkmcnt(0)" ::: "memory"); // all my buf reads done
        __builtin_amdgcn_sched_barrier(0);
        __builtin_amdgcn_s_barrier();             // ALL waves done reading buf
        if (t + 2 < NT) stage(t + 2);             // overwrite buf; flies across iters
        __builtin_amdgcn_s_setprio(1);
        #pragma unroll
        for (int kk = 0; kk < 2; kk++)
            #pragma unroll
            for (int m = 0; m < 4; m++)
                #pragma unroll
                for (int n = 0; n < 4; n++)
                    acc[4 + m][n] = __builtin_amdgcn_mfma_f32_16x16x32_bf16(af[kk][m], bfr[kk][n], acc[4 + m][n], 0, 0, 0);
        __builtin_amdgcn_s_setprio(0);
    }

    if constexpr (EPI == EPI_QKV) {
        // N=1536; 256-col panels are block-uniform: 0-1=Q, 2-3=K, 4-5=V.
        int region = (int)(colB0 >> 9);           // 0=Q, 1=K, 2=V
        if (region < 2) {
            bf16* dst = Cb + (long)region * (8192L * 512);
            int cb = ((int)colB0 & 511) + wn4 * 64;
            #pragma unroll
            for (int m = 0; m < 8; m++)
                #pragma unroll
                for (int n = 0; n < 4; n++)
                    #pragma unroll
                    for (int j = 0; j < 4; j++) {
                        long row = rowA0 + wm2 * 128 + m * 16 + (lane >> 4) * 4 + j;
                        int c = cb + n * 16 + l15;
                        dst[row * 512 + c] = (bf16)acc[m][n][j];
                    }
        } else {
            bf16* vtb = Cb + 2L * 8192 * 512;
            int cb = ((int)colB0 - 1024) + wn4 * 64;
            #pragma unroll
            for (int m = 0; m < 8; m++)
                #pragma unroll
                for (int n = 0; n < 4; n++) {
                    long k0 = rowA0 + wm2 * 128 + m * 16 + (lane >> 4) * 4;
                    long b = k0 >> 11, k = k0 & 2047;
                    int c = cb + n * 16 + l15;
                    bf16x4 pk = { (bf16)acc[m][n][0], (bf16)acc[m][n][1],
                                  (bf16)acc[m][n][2], (bf16)acc[m][n][3] };
                    *(bf16x4*)&vtb[(b * 512 + c) * 2048 + k] = pk;
                }
        }
    } else {
        #pragma unroll
        for (int m = 0; m < 8; m++) {
            #pragma unroll
            for (int n = 0; n < 4; n++) {
                #pragma unroll
                for (int j = 0; j < 4; j++) {
                    long row = rowA0 + wm2 * 128 + m * 16 + (lane >> 4) * 4 + j;
                    long col = colB0 + wn4 * 64 + n * 16 + l15;
                    float v = acc[m][n][j];
                    if (EPI == EPI_BIAS_F32) {
                        Cf[row * N + col] = v + bias[col];
                    } else if (EPI == EPI_BIAS_F32_NT) {
                        // streaming output: bypass L2 so it holds A/B panels
                        __builtin_nontemporal_store(v + bias[col], &Cf[row * N + col]);
                    } else if (EPI == EPI_BIAS_RELU_BF16) {
                        Cb[row * N + col] = (bf16)fmaxf(v + bias[col], 0.0f);
                    } else if (EPI == EPI_F32) {
                        Cf[row * N + col] = v;
                    }
                }
            }
        }
    }
}

// ---------------------------------------------------------------- launch
extern "C" void kernel_launch(void* const* d_in, const int* in_sizes, int n_in,
                              void* d_out, int out_size, void* d_ws, size_t ws_size,
                              hipStream_t stream) {
    const int*   x       = (const int*)d_in[0];
    const float* word_emb = (const float*)d_in[1];
    const float* pos_emb  = (const float*)d_in[2];
    const float* Wq = (const float*)d_in[3];
    const float* Wk = (const float*)d_in[4];
    const float* Wv = (const float*)d_in[5];
    const float* g1 = (const float*)d_in[6];
    const float* b1 = (const float*)d_in[7];
    const float* w_ffn1 = (const float*)d_in[8];
    const float* b_ffn1 = (const float*)d_in[9];
    const float* w_ffn2 = (const float*)d_in[10];
    const float* b_ffn2 = (const float*)d_in[11];
    const float* g2 = (const float*)d_in[12];
    const float* b2 = (const float*)d_in[13];
    const float* w_vocab = (const float*)d_in[14];
    const float* b_vocab = (const float*)d_in[15];
    float* out = (float*)d_out;

    char* w = (char*)d_ws;
    auto alloc = [&](size_t bytes) { char* p = w; w += (bytes + 255) & ~255ULL; return p; };
    // NOTE: wqb/wkb/wvb must stay contiguous ([1536 x 512] fused weight);
    //       qb/kb/vt must stay contiguous (EPI_QKV writes all three off qb).
    bf16* wqb   = (bf16*)alloc(512 * 512 * 2);
    bf16* wkb   = (bf16*)alloc(512 * 512 * 2);
    bf16* wvb   = (bf16*)alloc(512 * 512 * 2);
    bf16* w1b   = (bf16*)alloc(2048 * 512 * 2);
    bf16* w2b   = (bf16*)alloc(512 * 2048 * 2);
    bf16* wvocb = (bf16*)alloc((size_t)32000 * 512 * 2);
    float* embf = (float*)alloc((size_t)8192 * 512 * 4);
    bf16* embb  = (bf16*)alloc((size_t)8192 * 512 * 2);   // also final_b (aliased)
    bf16* qb    = (bf16*)alloc((size_t)8192 * 512 * 2);
    bf16* kb    = (bf16*)alloc((size_t)8192 * 512 * 2);   // also out1_b (aliased)
    bf16* vt    = (bf16*)alloc((size_t)8192 * 512 * 2);
    float* scores = (float*)alloc((size_t)4 * 2048 * 2048 * 4); // also ffn1_b (aliased)
    bf16* probs = (bf16*)alloc((size_t)4 * 2048 * 2048 * 2);
    float* ctx  = (float*)alloc((size_t)8192 * 512 * 4);
    float* out1f = (float*)alloc((size_t)8192 * 512 * 4);
    float* ffn2f = (float*)alloc((size_t)8192 * 512 * 4);
    bf16* ffn1b = (bf16*)scores;   // alias: scores dead after softmax
    bf16* out1b = kb;              // alias: kb dead after scores GEMM
    bf16* finalb = embb;           // alias: embb dead after QKV GEMM

    const float qscale = 0.044194173824159216f; // 1/sqrt(512)

    // one launch converts all six weight tensors (Wq pre-scaled by 1/sqrt(d_k))
    CvtArgs ca;
    ca.src[0] = Wq;      ca.dst[0] = wqb;   ca.n4[0] = 512 * 512 / 4;          ca.scale[0] = qscale;
    ca.src[1] = Wk;      ca.dst[1] = wkb;   ca.n4[1] = 512 * 512 / 4;          ca.scale[1] = 1.0f;
    ca.src[2] = Wv;      ca.dst[2] = wvb;   ca.n4[2] = 512 * 512 / 4;          ca.scale[2] = 1.0f;
    ca.src[3] = w_ffn1;  ca.dst[3] = w1b;   ca.n4[3] = 2048 * 512 / 4;         ca.scale[3] = 1.0f;
    ca.src[4] = w_ffn2;  ca.dst[4] = w2b;   ca.n4[4] = 512 * 2048 / 4;         ca.scale[4] = 1.0f;
    ca.src[5] = w_vocab; ca.dst[5] = wvocb; ca.n4[5] = (long)32000 * 512 / 4;  ca.scale[5] = 1.0f;
    cvt_all<<<dim3(256, 6), 256, 0, stream>>>(ca);

    embed_kernel<<<8192, 128, 0, stream>>>(x, word_emb, pos_emb, embf, embb);

    // fused Q|K|V projection: emb[8192x512] @ Wqkv^T[1536x512] -> qb,kb,vt
    gemm256<EPI_QKV, true, false, 0, 8><<<dim3(6, 32, 1), 512, 0, stream>>>(
        embb, wqb, nullptr, qb, nullptr, 1536, 512, 0, 0, 0);

    // scores = Q @ K^T (batched 256^2 deep pipeline, causal block skip)
    gemm256<EPI_F32, true, true, 0, 8><<<dim3(8, 8, 4), 512, 0, stream>>>(
        qb, kb, scores, nullptr, nullptr, 2048, 512,
        (long)2048 * 512, (long)2048 * 512, (long)2048 * 2048);

    softmax_causal<<<8192, 256, 0, stream>>>(scores, probs);

    // context = P @ V (B operand = V^T, batched, causal K-limit)
    gemm_bt<EPI_F32, false, true, false, ZB_BATCH><<<dim3(4, 16, 4), 256, 0, stream>>>(
        probs, vt, ctx, nullptr, nullptr, 1.0f, 2048, 512, 2048, 2048,
        (long)2048 * 2048, (long)512 * 2048, (long)2048 * 512);

    ln_kernel<true><<<8192, 128, 0, stream>>>(embf, ctx, g1, b1, out1f, out1b);

    // ffn1 = relu(out1 @ W1^T + b1)  -- 256^2 deep pipeline
    gemm256<EPI_BIAS_RELU_BF16, true, false, 0, 8><<<dim3(8, 32, 1), 512, 0, stream>>>(
        out1b, w1b, nullptr, ffn1b, b_ffn1, 2048, 512, 0, 0, 0);

    // ffn2 = ffn1 @ W2^T + b2  (N=512 -> keep 128^2)
    gemm_bt<EPI_BIAS_F32, false, false, false, ZB_BATCH><<<dim3(4, 64, 1), 256, 0, stream>>>(
        ffn1b, w2b, ffn2f, nullptr, b_ffn2, 1.0f, 8192, 512, 2048, 2048, 0, 0, 0);

    ln_kernel<false><<<8192, 128, 0, stream>>>(out1f, ffn2f, g2, b2, nullptr, finalb);

    // logits = final @ w_vocab^T + b_vocab  -- BK=64 deep pipeline, 25 column
    // bands of 5 col-tiles: B-panel reuse slice 1.3 MB (L2-resident per XCD);
    // non-temporal C stores keep the 1.05 GB write stream out of L2.
    gemm256<EPI_BIAS_F32_NT, true, false, 5, 8><<<dim3(125, 32, 1), 512, 0, stream>>>(
        finalb, wvocb, out, nullptr, b_vocab, 32000, 512, 0, 0, 0);
}

// Round 8
// 553.834 us; speedup vs baseline: 1.2968x; 1.0509x over previous
//
#include <hip/hip_runtime.h>
#include <hip/hip_bf16.h>

typedef __bf16 bf16;
typedef __attribute__((ext_vector_type(4))) __bf16 bf16x4;
typedef __attribute__((ext_vector_type(8))) __bf16 bf16x8;
typedef __attribute__((ext_vector_type(4))) float f32x4;

__device__ inline void gload_lds16(const bf16* g, bf16* l) {
    __builtin_amdgcn_global_load_lds(
        (const __attribute__((address_space(1))) void*)g,
        (__attribute__((address_space(3))) void*)l, 16, 0, 0);
}

// ---------------------------------------------------------------- fused conversions
struct CvtArgs {
    const float* src[6];
    bf16* dst[6];
    long n4[6];
    float scale[6];
};
__global__ void cvt_all(CvtArgs a) {
    int j = blockIdx.y;
    const float* __restrict__ src = a.src[j];
    bf16* __restrict__ dst = a.dst[j];
    long n4 = a.n4[j];
    float sc = a.scale[j];
    long i = (long)blockIdx.x * blockDim.x + threadIdx.x;
    long stride = (long)gridDim.x * blockDim.x;
    for (; i < n4; i += stride) {
        float4 v = ((const float4*)src)[i];
        bf16x4 o = { (bf16)(v.x * sc), (bf16)(v.y * sc), (bf16)(v.z * sc), (bf16)(v.w * sc) };
        ((bf16x4*)dst)[i] = o;
    }
}

// ---------------------------------------------------------------- embedding
__global__ void embed_kernel(const int* __restrict__ x, const float* __restrict__ we,
                             const float* __restrict__ pe, float* __restrict__ emb_f,
                             bf16* __restrict__ emb_b) {
    int row = blockIdx.x;            // 0..8191  (b*2048 + s)
    int c   = threadIdx.x;           // 0..127
    int tok = x[row];
    int s   = row & 2047;
    float4 w = ((const float4*)we)[(long)tok * 128 + c];
    float4 p = ((const float4*)pe)[(long)s * 128 + c];
    float4 e = { w.x + p.x, w.y + p.y, w.z + p.z, w.w + p.w };
    ((float4*)emb_f)[(long)row * 128 + c] = e;
    bf16x4 eb = { (bf16)e.x, (bf16)e.y, (bf16)e.z, (bf16)e.w };
    ((bf16x4*)emb_b)[(long)row * 128 + c] = eb;
}

// ---------------------------------------------------------------- layernorm
template<bool WF32>
__global__ void ln_kernel(const float* __restrict__ a, const float* __restrict__ bres,
                          const float* __restrict__ g, const float* __restrict__ bb,
                          float* __restrict__ of, bf16* __restrict__ ob) {
    int row = blockIdx.x;            // 8192
    int t   = threadIdx.x;           // 128
    float4 xa = ((const float4*)a)[(long)row * 128 + t];
    float4 xb = ((const float4*)bres)[(long)row * 128 + t];
    float4 xv = { xa.x + xb.x, xa.y + xb.y, xa.z + xb.z, xa.w + xb.w };
    float s  = xv.x + xv.y + xv.z + xv.w;
    float sq = xv.x * xv.x + xv.y * xv.y + xv.z * xv.z + xv.w * xv.w;
    #pragma unroll
    for (int o = 32; o > 0; o >>= 1) {
        s  += __shfl_xor(s, o);
        sq += __shfl_xor(sq, o);
    }
    __shared__ float rs[2], rq[2];
    int wid = t >> 6;
    if ((t & 63) == 0) { rs[wid] = s; rq[wid] = sq; }
    __syncthreads();
    s = rs[0] + rs[1]; sq = rq[0] + rq[1];
    float mu   = s * (1.0f / 512.0f);
    float var  = sq * (1.0f / 512.0f) - mu * mu;
    float rstd = rsqrtf(var + 1e-5f);
    float4 gv = ((const float4*)g)[t];
    float4 bv = ((const float4*)bb)[t];
    float4 y = { (xv.x - mu) * rstd * gv.x + bv.x,
                 (xv.y - mu) * rstd * gv.y + bv.y,
                 (xv.z - mu) * rstd * gv.z + bv.z,
                 (xv.w - mu) * rstd * gv.w + bv.w };
    if (WF32) ((float4*)of)[(long)row * 128 + t] = y;
    bf16x4 yb = { (bf16)y.x, (bf16)y.y, (bf16)y.z, (bf16)y.w };
    ((bf16x4*)ob)[(long)row * 128 + t] = yb;
}

// ---------------------------------------------------------------- causal softmax
__global__ void softmax_causal(const float* __restrict__ sc, bf16* __restrict__ pr) {
    int row = blockIdx.x;            // 8192
    int z = row >> 11, q = row & 2047;
    const float* srow = sc + ((long)z * 2048 + q) * 2048;
    bf16*        prow = pr + ((long)z * 2048 + q) * 2048;
    int t = threadIdx.x;             // 256, each handles 8 cols
    float v[8];
    int c0 = t * 8;
    if (t <= (q >> 3)) {
        float4 v0 = ((const float4*)srow)[t * 2];
        float4 v1 = ((const float4*)srow)[t * 2 + 1];
        v[0] = v0.x; v[1] = v0.y; v[2] = v0.z; v[3] = v0.w;
        v[4] = v1.x; v[5] = v1.y; v[6] = v1.z; v[7] = v1.w;
    } else {
        #pragma unroll
        for (int j = 0; j < 8; j++) v[j] = -1e30f;
    }
    float mx = -1e30f;
    #pragma unroll
    for (int j = 0; j < 8; j++) {
        if (c0 + j > q) v[j] = -1e30f;
        mx = fmaxf(mx, v[j]);
    }
    int lane = t & 63, wid = t >> 6;
    #pragma unroll
    for (int o = 32; o > 0; o >>= 1) mx = fmaxf(mx, __shfl_xor(mx, o));
    __shared__ float redm[4], reds[4];
    if (lane == 0) redm[wid] = mx;
    __syncthreads();
    mx = fmaxf(fmaxf(redm[0], redm[1]), fmaxf(redm[2], redm[3]));
    float p[8]; float sum = 0.f;
    #pragma unroll
    for (int j = 0; j < 8; j++) {
        p[j] = (c0 + j <= q) ? __expf(v[j] - mx) : 0.f;
        sum += p[j];
    }
    #pragma unroll
    for (int o = 32; o > 0; o >>= 1) sum += __shfl_xor(sum, o);
    if (lane == 0) reds[wid] = sum;
    __syncthreads();
    sum = reds[0] + reds[1] + reds[2] + reds[3];
    float inv = 1.0f / sum;
    int wlim = ((q >> 7) + 1) * 128;             // causal 128-block boundary
    if (c0 < wlim) {
        bf16x8 o;
        #pragma unroll
        for (int j = 0; j < 8; j++) o[j] = (bf16)(p[j] * inv);
        *(bf16x8*)&prow[c0] = o;
    }
}

// ---------------------------------------------------------------- epilogue tags
enum { EPI_F32 = 0, EPI_BF16 = 1, EPI_VT = 2, EPI_BIAS_RELU_BF16 = 3, EPI_BIAS_F32 = 4,
       EPI_QKV = 5, EPI_BIAS_F32_NT = 6 };
enum { ZB_BATCH = 0 };

// ---------------------------------------------------------------- 128^2 GEMM (proven)
template<int EPI, bool CAUSAL_SKIP, bool CAUSAL_K, bool XCD, int ZMODE>
__global__ __launch_bounds__(256)
void gemm_bt(const bf16* __restrict__ A, const bf16* __restrict__ B,
             float* __restrict__ Cf, bf16* __restrict__ Cb,
             const float* __restrict__ bias, float scale,
             int M, int N, int K, int Krow, long sA, long sB, long sC) {
    int br, bc;
    if (XCD) {
        int nwg = gridDim.x * gridDim.y;         // caller ensures %8==0
        int lin = blockIdx.y * gridDim.x + blockIdx.x;
        lin = (lin & 7) * (nwg >> 3) + (lin >> 3);
        br = lin / gridDim.x; bc = lin - br * gridDim.x;
    } else { br = blockIdx.y; bc = blockIdx.x; }
    int z = blockIdx.z;
    A += (long)z * sA; B += (long)z * sB; Cf += (long)z * sC;
    if (CAUSAL_SKIP && bc > br) return;
    int Kext = CAUSAL_K ? min(K, (br + 1) * 128) : K;
    __shared__ bf16 As[128 * 64];
    __shared__ bf16 Bs[128 * 64];
    int tid = threadIdx.x;
    int lane = tid & 63, wid = tid >> 6;
    int wm = (wid >> 1) * 64, wn = (wid & 1) * 64;
    f32x4 acc[4][4] = {};
    int rowA0 = br * 128, colB0 = bc * 128;
    int rsub = lane >> 3;
    int csub = ((lane & 7) ^ rsub) * 8;            // pre-swizzled source col
    int rdsw = (lane & 7) * 8;                     // read-side XOR
    for (int kt = 0; kt < Kext; kt += 64) {
        const bf16* Ag = A + (long)rowA0 * Krow + kt;
        const bf16* Bg = B + (long)colB0 * Krow + kt;
        #pragma unroll
        for (int i = 0; i < 4; i++) {
            int seg = wid * 4 + i;
            int r = seg * 8 + rsub;
            gload_lds16(&Ag[(long)r * Krow + csub], &As[seg * 512]);
            gload_lds16(&Bg[(long)r * Krow + csub], &Bs[seg * 512]);
        }
        __syncthreads();
        #pragma unroll
        for (int kk = 0; kk < 2; kk++) {
            bf16x8 af[4], bfr[4];
            int ko = (kk * 32 + (lane >> 4) * 8) ^ rdsw;
            #pragma unroll
            for (int m = 0; m < 4; m++) af[m]  = *(const bf16x8*)&As[(wm + m * 16 + (lane & 15)) * 64 + ko];
            #pragma unroll
            for (int n = 0; n < 4; n++) bfr[n] = *(const bf16x8*)&Bs[(wn + n * 16 + (lane & 15)) * 64 + ko];
            #pragma unroll
            for (int m = 0; m < 4; m++)
                #pragma unroll
                for (int n = 0; n < 4; n++)
                    acc[m][n] = __builtin_amdgcn_mfma_f32_16x16x32_bf16(af[m], bfr[n], acc[m][n], 0, 0, 0);
        }
        __syncthreads();
    }
    #pragma unroll
    for (int m = 0; m < 4; m++) {
        #pragma unroll
        for (int n = 0; n < 4; n++) {
            #pragma unroll
            for (int j = 0; j < 4; j++) {
                int row = rowA0 + wm + m * 16 + (lane >> 4) * 4 + j;
                int col = colB0 + wn + n * 16 + (lane & 15);
                float v = acc[m][n][j];
                if (EPI == EPI_F32) {
                    Cf[(long)row * N + col] = v;        // z-offset already applied
                } else if (EPI == EPI_BF16) {
                    Cb[(long)row * N + col] = (bf16)(v * scale);
                } else if (EPI == EPI_VT) {
                    int b = row >> 11, k = row & 2047;
                    Cb[((long)b * 512 + col) * 2048 + k] = (bf16)v;
                } else if (EPI == EPI_BIAS_RELU_BF16) {
                    float y = fmaxf(v + bias[col], 0.0f);
                    Cb[(long)row * N + col] = (bf16)y;
                } else if (EPI == EPI_BIAS_F32) {
                    Cf[(long)row * N + col] = v + bias[col];
                }
            }
        }
    }
}

// ---------------------------------------------------------------- 256^2 deep-pipeline GEMM (BK=64)
// BANDW > 0: column-band tile order (see R6/R7 notes).
template<int EPI, bool XCD, bool CSKIP, int BANDW, int NT>
__global__ __launch_bounds__(512)
void gemm256(const bf16* __restrict__ A, const bf16* __restrict__ B,
             float* __restrict__ Cf, bf16* __restrict__ Cb,
             const float* __restrict__ bias, int N, int K,
             long sA, long sB, long sC) {
    int br, bc;
    if (XCD) {
        int nwg = gridDim.x * gridDim.y;          // caller ensures %8==0
        int lin = blockIdx.y * gridDim.x + blockIdx.x;
        lin = (lin & 7) * (nwg >> 3) + (lin >> 3);
        if (BANDW > 0) {
            int per = BANDW * gridDim.y;          // blocks per band
            int band = lin / per, w2 = lin - band * per;
            br = w2 / BANDW; bc = band * BANDW + (w2 - br * BANDW);
        } else {
            br = lin / gridDim.x; bc = lin - br * gridDim.x;
        }
    } else { br = blockIdx.y; bc = blockIdx.x; }
    if (CSKIP && bc > br) return;                 // causal skip at 256-tile granularity
    int z = blockIdx.z;
    A  += (long)z * sA;
    B  += (long)z * sB;
    Cf += (long)z * sC;
    __shared__ bf16 lds[2][2][256 * 64];          // [buf][A/B] = 128 KiB
    int tid = threadIdx.x;
    int lane = tid & 63, wid = tid >> 6;
    int wm2 = wid >> 2, wn4 = wid & 3;
    long rowA0 = (long)br * 256, colB0 = (long)bc * 256;
    int rsub = lane >> 3;
    int csw  = ((lane & 7) ^ rsub) * 8;           // pre-swizzled source col
    int l15 = lane & 15;
    int rdxor = (lane & 7) << 3;
    int kbase = (lane >> 4) * 8;
    const bf16* Abase = A + rowA0 * K;
    const bf16* Bbase = B + colB0 * K;
    f32x4 acc[8][4] = {};

    auto stage = [&](int t) {
        int buf = t & 1;
        const bf16* Ag = Abase + t * 64;
        const bf16* Bg = Bbase + t * 64;
        #pragma unroll
        for (int i = 0; i < 4; i++) {
            int seg = wid * 4 + i;                // 0..31
            long r = seg * 8 + rsub;
            gload_lds16(&Ag[r * K + csw], &lds[buf][0][seg * 512]);
        }
        #pragma unroll
        for (int i = 0; i < 4; i++) {
            int seg = wid * 4 + i;
            long r = seg * 8 + rsub;
            gload_lds16(&Bg[r * K + csw], &lds[buf][1][seg * 512]);
        }
    };

    stage(0);
    stage(1);

    for (int t = 0; t < NT; t++) {
        int buf = t & 1;
        if (t == NT - 1) asm volatile("s_waitcnt vmcnt(0)" ::: "memory");
        else             asm volatile("s_waitcnt vmcnt(8)" ::: "memory");
        __builtin_amdgcn_s_barrier();             // everyone's tile-t data visible
        const bf16* As = lds[buf][0];
        const bf16* Bs = lds[buf][1];
        bf16x8 bfr[2][4], af[2][4];
        #pragma unroll
        for (int kk = 0; kk < 2; kk++)
            #pragma unroll
            for (int n = 0; n < 4; n++) {
                int r = wn4 * 64 + n * 16 + l15;
                bfr[kk][n] = *(const bf16x8*)&Bs[r * 64 + ((kk * 32 + kbase) ^ rdxor)];
            }
        #pragma unroll
        for (int kk = 0; kk < 2; kk++)
            #pragma unroll
            for (int m = 0; m < 4; m++) {
                int r = wm2 * 128 + m * 16 + l15;
                af[kk][m] = *(const bf16x8*)&As[r * 64 + ((kk * 32 + kbase) ^ rdxor)];
            }
        __builtin_amdgcn_s_setprio(1);
        #pragma unroll
        for (int kk = 0; kk < 2; kk++)
            #pragma unroll
            for (int m = 0; m < 4; m++)
                #pragma unroll
                for (int n = 0; n < 4; n++)
                    acc[m][n] = __builtin_amdgcn_mfma_f32_16x16x32_bf16(af[kk][m], bfr[kk][n], acc[m][n], 0, 0, 0);
        __builtin_amdgcn_s_setprio(0);
        // second half of A rows
        #pragma unroll
        for (int kk = 0; kk < 2; kk++)
            #pragma unroll
            for (int m = 0; m < 4; m++) {
                int r = wm2 * 128 + 64 + m * 16 + l15;
                af[kk][m] = *(const bf16x8*)&As[r * 64 + ((kk * 32 + kbase) ^ rdxor)];
            }
        asm volatile("s_waitcnt lgkmcnt(0)" ::: "memory"); // all my buf reads done
        __builtin_amdgcn_sched_barrier(0);
        __builtin_amdgcn_s_barrier();             // ALL waves done reading buf
        if (t + 2 < NT) stage(t + 2);             // overwrite buf; flies across iters
        __builtin_amdgcn_s_setprio(1);
        #pragma unroll
        for (int kk = 0; kk < 2; kk++)
            #pragma unroll
            for (int m = 0; m < 4; m++)
                #pragma unroll
                for (int n = 0; n < 4; n++)
                    acc[4 + m][n] = __builtin_amdgcn_mfma_f32_16x16x32_bf16(af[kk][m], bfr[kk][n], acc[4 + m][n], 0, 0, 0);
        __builtin_amdgcn_s_setprio(0);
    }

    if constexpr (EPI == EPI_QKV) {
        // N=1536; 256-col panels are block-uniform: 0-1=Q, 2-3=K, 4-5=V.
        int region = (int)(colB0 >> 9);           // 0=Q, 1=K, 2=V
        if (region < 2) {
            bf16* dst = Cb + (long)region * (8192L * 512);
            int cb = ((int)colB0 & 511) + wn4 * 64;
            #pragma unroll
            for (int m = 0; m < 8; m++)
                #pragma unroll
                for (int n = 0; n < 4; n++)
                    #pragma unroll
                    for (int j = 0; j < 4; j++) {
                        long row = rowA0 + wm2 * 128 + m * 16 + (lane >> 4) * 4 + j;
                        int c = cb + n * 16 + l15;
                        dst[row * 512 + c] = (bf16)acc[m][n][j];
                    }
        } else {
            bf16* vtb = Cb + 2L * 8192 * 512;
            int cb = ((int)colB0 - 1024) + wn4 * 64;
            #pragma unroll
            for (int m = 0; m < 8; m++)
                #pragma unroll
                for (int n = 0; n < 4; n++) {
                    long k0 = rowA0 + wm2 * 128 + m * 16 + (lane >> 4) * 4;
                    long b = k0 >> 11, k = k0 & 2047;
                    int c = cb + n * 16 + l15;
                    bf16x4 pk = { (bf16)acc[m][n][0], (bf16)acc[m][n][1],
                                  (bf16)acc[m][n][2], (bf16)acc[m][n][3] };
                    *(bf16x4*)&vtb[(b * 512 + c) * 2048 + k] = pk;
                }
        }
    } else {
        #pragma unroll
        for (int m = 0; m < 8; m++) {
            #pragma unroll
            for (int n = 0; n < 4; n++) {
                #pragma unroll
                for (int j = 0; j < 4; j++) {
                    long row = rowA0 + wm2 * 128 + m * 16 + (lane >> 4) * 4 + j;
                    long col = colB0 + wn4 * 64 + n * 16 + l15;
                    float v = acc[m][n][j];
                    if (EPI == EPI_BIAS_F32) {
                        Cf[row * N + col] = v + bias[col];
                    } else if (EPI == EPI_BIAS_F32_NT) {
                        __builtin_nontemporal_store(v + bias[col], &Cf[row * N + col]);
                    } else if (EPI == EPI_BIAS_RELU_BF16) {
                        Cb[row * N + col] = (bf16)fmaxf(v + bias[col], 0.0f);
                    } else if (EPI == EPI_F32) {
                        Cf[row * N + col] = v;
                    }
                }
            }
        }
    }
}

// ---------------------------------------------------------------- vocab GEMM: 128^2 tile,
// BK=64 double-buffered, 256 thr (4 waves, per-wave 64x64), counted vmcnt.
// 64 KiB LDS + ~120 VGPR -> TWO co-resident blocks/CU: block j+1's compute
// covers block j's end-of-kernel store drain and block j+2's prologue ramp
// (the 1-block/CU serialization that capped gemm256 at ~845 TF here).
// Column-band order (BANDB bc-tiles per band) + XCD swizzle keeps the
// concurrent B slice ~1.25 MB/XCD (L2-resident); NT stores keep the 1.05 GB
// output stream out of L2. Staging/swizzle copied verbatim from gemm_bt
// (proven); schedule from gemm256 (proven).
template<int BANDB>
__global__ __launch_bounds__(256)
void gemm128v(const bf16* __restrict__ A, const bf16* __restrict__ B,
              float* __restrict__ C, const float* __restrict__ bias,
              int N, int K) {
    const int NBR = 64;                            // 8192/128 row-tiles
    const int NT  = 8;                             // K=512 / 64
    int nwg = gridDim.x;                           // 16000 (%8==0)
    int lin = blockIdx.x;
    lin = (lin & 7) * (nwg >> 3) + (lin >> 3);     // XCD-contiguous chunks
    int per = BANDB * NBR;
    int band = lin / per, w2 = lin - band * per;
    int br = w2 / BANDB, bc = band * BANDB + (w2 - br * BANDB);

    __shared__ bf16 lds[2][2][128 * 64];           // 64 KiB -> 2 blocks/CU
    int tid = threadIdx.x;
    int lane = tid & 63, wid = tid >> 6;
    int wm = (wid >> 1) * 64, wn = (wid & 1) * 64;
    int rsub = lane >> 3;
    int csub = ((lane & 7) ^ rsub) * 8;            // pre-swizzled source col
    int rdsw = (lane & 7) * 8;                     // read-side XOR
    long rowA0 = (long)br * 128, colB0 = (long)bc * 128;
    const bf16* Abase = A + rowA0 * K;
    const bf16* Bbase = B + colB0 * K;
    f32x4 acc[4][4] = {};

    auto stage = [&](int t) {                      // 8 VMEM issues/thread
        int buf = t & 1;
        const bf16* Ag = Abase + t * 64;
        const bf16* Bg = Bbase + t * 64;
        #pragma unroll
        for (int i = 0; i < 4; i++) {
            int seg = wid * 4 + i;                 // 0..15
            long r = seg * 8 + rsub;
            gload_lds16(&Ag[r * K + csub], &lds[buf][0][seg * 512]);
        }
        #pragma unroll
        for (int i = 0; i < 4; i++) {
            int seg = wid * 4 + i;
            long r = seg * 8 + rsub;
            gload_lds16(&Bg[r * K + csub], &lds[buf][1][seg * 512]);
        }
    };

    stage(0);
    stage(1);

    for (int t = 0; t < NT; t++) {
        int buf = t & 1;
        if (t == NT - 1) asm volatile("s_waitcnt vmcnt(0)" ::: "memory");
        else             asm volatile("s_waitcnt vmcnt(8)" ::: "memory");
        __builtin_amdgcn_s_barrier();              // tile-t data visible
        const bf16* As = lds[buf][0];
        const bf16* Bs = lds[buf][1];
        __builtin_amdgcn_s_setprio(1);
        #pragma unroll
        for (int kk = 0; kk < 2; kk++) {
            bf16x8 af[4], bfr[4];
            int ko = (kk * 32 + (lane >> 4) * 8) ^ rdsw;
            #pragma unroll
            for (int m = 0; m < 4; m++) af[m]  = *(const bf16x8*)&As[(wm + m * 16 + (lane & 15)) * 64 + ko];
            #pragma unroll
            for (int n = 0; n < 4; n++) bfr[n] = *(const bf16x8*)&Bs[(wn + n * 16 + (lane & 15)) * 64 + ko];
            #pragma unroll
            for (int m = 0; m < 4; m++)
                #pragma unroll
                for (int n = 0; n < 4; n++)
                    acc[m][n] = __builtin_amdgcn_mfma_f32_16x16x32_bf16(af[m], bfr[n], acc[m][n], 0, 0, 0);
        }
        __builtin_amdgcn_s_setprio(0);
        asm volatile("s_waitcnt lgkmcnt(0)" ::: "memory"); // my buf reads done
        __builtin_amdgcn_sched_barrier(0);
        __builtin_amdgcn_s_barrier();              // ALL waves done reading buf
        if (t + 2 < NT) stage(t + 2);              // overwrite buf
    }

    #pragma unroll
    for (int m = 0; m < 4; m++) {
        #pragma unroll
        for (int n = 0; n < 4; n++) {
            int col = (int)colB0 + wn + n * 16 + (lane & 15);
            float bcol = bias[col];
            #pragma unroll
            for (int j = 0; j < 4; j++) {
                long row = rowA0 + wm + m * 16 + (lane >> 4) * 4 + j;
                __builtin_nontemporal_store(acc[m][n][j] + bcol, &C[row * N + col]);
            }
        }
    }
}

// ---------------------------------------------------------------- launch
extern "C" void kernel_launch(void* const* d_in, const int* in_sizes, int n_in,
                              void* d_out, int out_size, void* d_ws, size_t ws_size,
                              hipStream_t stream) {
    const int*   x       = (const int*)d_in[0];
    const float* word_emb = (const float*)d_in[1];
    const float* pos_emb  = (const float*)d_in[2];
    const float* Wq = (const float*)d_in[3];
    const float* Wk = (const float*)d_in[4];
    const float* Wv = (const float*)d_in[5];
    const float* g1 = (const float*)d_in[6];
    const float* b1 = (const float*)d_in[7];
    const float* w_ffn1 = (const float*)d_in[8];
    const float* b_ffn1 = (const float*)d_in[9];
    const float* w_ffn2 = (const float*)d_in[10];
    const float* b_ffn2 = (const float*)d_in[11];
    const float* g2 = (const float*)d_in[12];
    const float* b2 = (const float*)d_in[13];
    const float* w_vocab = (const float*)d_in[14];
    const float* b_vocab = (const float*)d_in[15];
    float* out = (float*)d_out;

    char* w = (char*)d_ws;
    auto alloc = [&](size_t bytes) { char* p = w; w += (bytes + 255) & ~255ULL; return p; };
    // NOTE: wqb/wkb/wvb must stay contiguous ([1536 x 512] fused weight);
    //       qb/kb/vt must stay contiguous (EPI_QKV writes all three off qb).
    bf16* wqb   = (bf16*)alloc(512 * 512 * 2);
    bf16* wkb   = (bf16*)alloc(512 * 512 * 2);
    bf16* wvb   = (bf16*)alloc(512 * 512 * 2);
    bf16* w1b   = (bf16*)alloc(2048 * 512 * 2);
    bf16* w2b   = (bf16*)alloc(512 * 2048 * 2);
    bf16* wvocb = (bf16*)alloc((size_t)32000 * 512 * 2);
    float* embf = (float*)alloc((size_t)8192 * 512 * 4);
    bf16* embb  = (bf16*)alloc((size_t)8192 * 512 * 2);   // also final_b (aliased)
    bf16* qb    = (bf16*)alloc((size_t)8192 * 512 * 2);
    bf16* kb    = (bf16*)alloc((size_t)8192 * 512 * 2);   // also out1_b (aliased)
    bf16* vt    = (bf16*)alloc((size_t)8192 * 512 * 2);
    float* scores = (float*)alloc((size_t)4 * 2048 * 2048 * 4); // also ffn1_b (aliased)
    bf16* probs = (bf16*)alloc((size_t)4 * 2048 * 2048 * 2);
    float* ctx  = (float*)alloc((size_t)8192 * 512 * 4);
    float* out1f = (float*)alloc((size_t)8192 * 512 * 4);
    float* ffn2f = (float*)alloc((size_t)8192 * 512 * 4);
    bf16* ffn1b = (bf16*)scores;   // alias: scores dead after softmax
    bf16* out1b = kb;              // alias: kb dead after scores GEMM
    bf16* finalb = embb;           // alias: embb dead after QKV GEMM

    const float qscale = 0.044194173824159216f; // 1/sqrt(512)

    // one launch converts all six weight tensors (Wq pre-scaled by 1/sqrt(d_k))
    CvtArgs ca;
    ca.src[0] = Wq;      ca.dst[0] = wqb;   ca.n4[0] = 512 * 512 / 4;          ca.scale[0] = qscale;
    ca.src[1] = Wk;      ca.dst[1] = wkb;   ca.n4[1] = 512 * 512 / 4;          ca.scale[1] = 1.0f;
    ca.src[2] = Wv;      ca.dst[2] = wvb;   ca.n4[2] = 512 * 512 / 4;          ca.scale[2] = 1.0f;
    ca.src[3] = w_ffn1;  ca.dst[3] = w1b;   ca.n4[3] = 2048 * 512 / 4;         ca.scale[3] = 1.0f;
    ca.src[4] = w_ffn2;  ca.dst[4] = w2b;   ca.n4[4] = 512 * 2048 / 4;         ca.scale[4] = 1.0f;
    ca.src[5] = w_vocab; ca.dst[5] = wvocb; ca.n4[5] = (long)32000 * 512 / 4;  ca.scale[5] = 1.0f;
    cvt_all<<<dim3(256, 6), 256, 0, stream>>>(ca);

    embed_kernel<<<8192, 128, 0, stream>>>(x, word_emb, pos_emb, embf, embb);

    // fused Q|K|V projection: emb[8192x512] @ Wqkv^T[1536x512] -> qb,kb,vt
    gemm256<EPI_QKV, true, false, 0, 8><<<dim3(6, 32, 1), 512, 0, stream>>>(
        embb, wqb, nullptr, qb, nullptr, 1536, 512, 0, 0, 0);

    // scores = Q @ K^T (batched 256^2 deep pipeline, causal block skip)
    gemm256<EPI_F32, true, true, 0, 8><<<dim3(8, 8, 4), 512, 0, stream>>>(
        qb, kb, scores, nullptr, nullptr, 2048, 512,
        (long)2048 * 512, (long)2048 * 512, (long)2048 * 2048);

    softmax_causal<<<8192, 256, 0, stream>>>(scores, probs);

    // context = P @ V (B operand = V^T, batched, causal K-limit)
    gemm_bt<EPI_F32, false, true, false, ZB_BATCH><<<dim3(4, 16, 4), 256, 0, stream>>>(
        probs, vt, ctx, nullptr, nullptr, 1.0f, 2048, 512, 2048, 2048,
        (long)2048 * 2048, (long)512 * 2048, (long)2048 * 512);

    ln_kernel<true><<<8192, 128, 0, stream>>>(embf, ctx, g1, b1, out1f, out1b);

    // ffn1 = relu(out1 @ W1^T + b1)  -- 256^2 deep pipeline
    gemm256<EPI_BIAS_RELU_BF16, true, false, 0, 8><<<dim3(8, 32, 1), 512, 0, stream>>>(
        out1b, w1b, nullptr, ffn1b, b_ffn1, 2048, 512, 0, 0, 0);

    // ffn2 = ffn1 @ W2^T + b2  (N=512 -> keep 128^2)
    gemm_bt<EPI_BIAS_F32, false, false, false, ZB_BATCH><<<dim3(4, 64, 1), 256, 0, stream>>>(
        ffn1b, w2b, ffn2f, nullptr, b_ffn2, 1.0f, 8192, 512, 2048, 2048, 0, 0, 0);

    ln_kernel<false><<<8192, 128, 0, stream>>>(out1f, ffn2f, g2, b2, nullptr, finalb);

    // logits = final @ w_vocab^T + b_vocab  -- 128^2 double-buffered pipeline,
    // 2 blocks/CU (64 KiB LDS): store drains and prologue ramps overlap across
    // co-resident blocks. 25 bands of 10 bc-tiles (250 = 25*10), NT stores.
    gemm128v<10><<<16000, 256, 0, stream>>>(finalb, wvocb, out, b_vocab, 32000, 512);
}